// Round 7
// baseline (2472.432 us; speedup 1.0000x reference)
//
#include <hip/hip_runtime.h>
#include <hip/hip_fp16.h>
#include <math.h>

#define N_ATOMS 100000
#define M_NBR 12
#define ORIG_FEA 92
#define NBR_FEA 41
#define AF 64
#define OUT2 128          // 2*AF
#define IN_FULL 169       // 2*AF + NBR_FEA
#define N_CONV 3
#define OUT_DIM 128
#define N_CRYSTALS 2000
#define ATOMS_PER 50
#define EPS 1e-5f

#define ZCH 16            // atoms per fallback edge-kernel block
#define EDGES (ZCH * M_NBR)          // 192
#define NF_STRIDE 44      // padded fp16 row stride (fallback path)
#define YB_ATOMS 80       // atoms per ysn block (100000 % 80 == 0)
#define YB_CHUNK 16

#define ZW_BLOCKS 1024    // wave-per-atom zstats grid (4 waves/SIMD exactly)
#define ZW_WAVES (ZW_BLOCKS * 4)

typedef _Float16 h4 __attribute__((ext_vector_type(4)));

// cheap softplus: log1p(t)->log(1+t) adds only ~2^-24 abs error (result feeds sums)
__device__ __forceinline__ float softplus_f(float x) {
    return fmaxf(x, 0.0f) + __logf(1.0f + __expf(-fabsf(x)));
}
__device__ __forceinline__ float sigmoid_f(float x) {
    return __builtin_amdgcn_rcpf(1.0f + __expf(-x));   // v_rcp_f32, ~1ulp
}
__device__ __forceinline__ void fma4(float4& a, float s, const float4& b) {
    a.x = fmaf(s, b.x, a.x); a.y = fmaf(s, b.y, a.y);
    a.z = fmaf(s, b.z, a.z); a.w = fmaf(s, b.w, a.w);
}
__device__ __forceinline__ float4 zero4() { return make_float4(0.f, 0.f, 0.f, 0.f); }

union H4 { uint2 u; __half2 h[2]; };
__device__ __forceinline__ void store_h4(__half* p, float4 v) {
    H4 t;
    t.h[0] = __floats2half2_rn(v.x, v.y);
    t.h[1] = __floats2half2_rn(v.z, v.w);
    *(uint2*)p = t.u;
}
__device__ __forceinline__ float4 load_h4(const __half* p) {
    H4 t; t.u = *(const uint2*)p;
    float2 a = __half22float2(t.h[0]);
    float2 b = __half22float2(t.h[1]);
    return make_float4(a.x, a.y, b.x, b.y);
}

// x[n][c] = b[c] + sum_k af[n][k]*W[k][c]   (c<64, k<92)
__global__ __launch_bounds__(256, 2) void k_embed(
    const float* __restrict__ af, const float* __restrict__ W,
    const float* __restrict__ b, float* __restrict__ x) {
  __shared__ __align__(16) float saf[64 * ORIG_FEA];
  int a0 = blockIdx.x * 64;
  int na = min(64, N_ATOMS - a0);
  int tid = threadIdx.x;
  int c = tid & 63, rgrp = tid >> 6;
  float w[ORIG_FEA];
#pragma unroll
  for (int k = 0; k < ORIG_FEA; ++k) w[k] = W[k * AF + c];
  int n4 = na * (ORIG_FEA / 4);
  const float4* g4 = (const float4*)(af + (size_t)a0 * ORIG_FEA);
  float4* s4 = (float4*)saf;
  for (int e = tid; e < n4; e += 256) s4[e] = g4[e];
  __syncthreads();
  float bc = b[c];
  for (int a = rgrp; a < na; a += 4) {
    float acc = bc;
    const float4* row = (const float4*)(saf + a * ORIG_FEA);
#pragma unroll
    for (int q = 0; q < ORIG_FEA / 4; ++q) {
      float4 v = row[q];
      acc = fmaf(v.x, w[4 * q], acc);
      acc = fmaf(v.y, w[4 * q + 1], acc);
      acc = fmaf(v.z, w[4 * q + 2], acc);
      acc = fmaf(v.w, w[4 * q + 3], acc);
    }
    x[(size_t)(a0 + a) * AF + c] = acc;
  }
}

// y GEMM: [100k x 64] @ [64 x 256] -> y_self[n][128], y_nbr[n][128].
__global__ __launch_bounds__(256, 2) void k_ysn(
    const float* __restrict__ x, const float* __restrict__ Wf,
    float* __restrict__ y_self, float* __restrict__ y_nbr) {
  __shared__ __align__(16) float sW2[64 * 256];
  __shared__ __align__(16) float sx[YB_CHUNK * AF];
  int tid = threadIdx.x;
  int cg = tid & 31, ag = tid >> 5;     // cg: ch-quad, ag: atom-pair
  int c0 = cg * 4;
  {  // stage W': cols 0..127 = Wf[0:64][:], cols 128..255 = Wf[64:128][:]
    float4* s4 = (float4*)sW2;
    const float4* g4 = (const float4*)Wf;
    for (int e = tid; e < 64 * 64; e += 256) {
      int r = e >> 6, q = e & 63;
      s4[r * 64 + q] = (q < 32) ? g4[r * 32 + q] : g4[(64 + r) * 32 + (q - 32)];
    }
  }
  int ab = blockIdx.x * YB_ATOMS;
  for (int cc = 0; cc < YB_ATOMS / YB_CHUNK; ++cc) {
    int a0 = ab + cc * YB_CHUNK;
    __syncthreads();
    {
      float4* s4 = (float4*)sx;
      const float4* g4 = (const float4*)(x + (size_t)a0 * AF);
      for (int e = tid; e < YB_CHUNK * AF / 4; e += 256) s4[e] = g4[e];
    }
    __syncthreads();
    float4 accs[2] = {zero4(), zero4()};
    float4 accn[2] = {zero4(), zero4()};
    for (int k0 = 0; k0 < AF; k0 += 4) {
      float4 av0 = *(const float4*)(sx + (ag * 2 + 0) * AF + k0);
      float4 av1 = *(const float4*)(sx + (ag * 2 + 1) * AF + k0);
#pragma unroll
      for (int kk = 0; kk < 4; ++kk) {
        float4 b0 = *(const float4*)(sW2 + (k0 + kk) * 256 + c0);
        float4 b1 = *(const float4*)(sW2 + (k0 + kk) * 256 + 128 + c0);
        float s0 = (kk == 0) ? av0.x : (kk == 1) ? av0.y : (kk == 2) ? av0.z : av0.w;
        float s1 = (kk == 0) ? av1.x : (kk == 1) ? av1.y : (kk == 2) ? av1.z : av1.w;
        fma4(accs[0], s0, b0); fma4(accn[0], s0, b1);
        fma4(accs[1], s1, b0); fma4(accn[1], s1, b1);
      }
    }
#pragma unroll
    for (int t = 0; t < 2; ++t) {
      size_t n = (size_t)(a0 + ag * 2 + t);
      *(float4*)(y_self + n * OUT2 + c0) = accs[t];
      *(float4*)(y_nbr + n * OUT2 + c0) = accn[t];
    }
  }
}

// ---------------- FAST PATH pass 1: wave-per-atom, W in registers ----------------
// Lane l owns channels {2l, 2l+1}. W must live in 82 VGPRs/wave.
// r6 lesson: with default heuristics the compiler targeted the <=64-VGPR occupancy
// bucket (VGPR_Count=56) and left the 82 W loads INSIDE the edge loop -> load-bound,
// VALUBusy 25%. amdgpu_waves_per_eu(2,4) raises the effective budget to ~128 VGPRs
// (grid is 4 waves/SIMD anyway), letting LICM keep W resident.
template <int WZ>
__global__ __attribute__((amdgpu_waves_per_eu(2, 4))) __launch_bounds__(256)
void k_zstats_w(
    const float* __restrict__ nbr_fea, const int* __restrict__ nidx,
    const float* __restrict__ y_self, const float* __restrict__ y_nbr,
    const float* __restrict__ Wf, const float* __restrict__ bf,
    float* __restrict__ gsum, float* __restrict__ gsumsq,
    __half* __restrict__ z16) {
  __shared__ float lsum[OUT2], lsumsq[OUT2];
  int tid = threadIdx.x;
  int lane = tid & 63;
  int wid = tid >> 6;                      // wave-uniform
  if (tid < OUT2) { lsum[tid] = 0.f; lsumsq[tid] = 0.f; }
  __syncthreads();
  const float* We = Wf + 2 * AF * OUT2;    // edge weight block [41][128]
  int c2 = lane * 2;
  float wlo[NBR_FEA], whi[NBR_FEA];
#pragma unroll
  for (int k = 0; k < NBR_FEA; ++k) {
    float2 wv = *(const float2*)(We + k * OUT2 + c2);
    wlo[k] = wv.x; whi[k] = wv.y;
  }
  float2 bv = *(const float2*)(bf + c2);
  float slo = 0.f, shi = 0.f, qlo = 0.f, qhi = 0.f;
  int w = __builtin_amdgcn_readfirstlane(blockIdx.x * 4 + wid);
  for (int a = w; a < N_ATOMS; a += ZW_WAVES) {
    float2 ys = *(const float2*)(y_self + (size_t)a * OUT2 + c2);
    float blo = ys.x + bv.x, bhi = ys.y + bv.y;
    const float* nfr = nbr_fea + (size_t)a * (M_NBR * NBR_FEA);
    const int* idxr = nidx + (size_t)a * M_NBR;
    int js[M_NBR];                         // uniform -> SGPRs (batched s_load)
#pragma unroll
    for (int m = 0; m < M_NBR; ++m) js[m] = idxr[m];
    // keep one y_nbr gather in flight under the FMA block
    float2 yn_next = *(const float2*)(y_nbr + (size_t)js[0] * OUT2 + c2);
#pragma unroll 2
    for (int m = 0; m < M_NBR; ++m) {
      float2 yn = yn_next;
      if (m + 1 < M_NBR)
        yn_next = *(const float2*)(y_nbr + (size_t)js[m + 1] * OUT2 + c2);
      float zlo = blo + yn.x, zhi = bhi + yn.y;
      const float* nf = nfr + m * NBR_FEA; // uniform row -> scalar loads
#pragma unroll
      for (int k = 0; k < NBR_FEA; ++k) {
        float s = nf[k];
        zlo = fmaf(s, wlo[k], zlo);
        zhi = fmaf(s, whi[k], zhi);
      }
      if (WZ) {
        __half2 h = __floats2half2_rn(zlo, zhi);
        *(__half2*)(z16 + ((size_t)a * M_NBR + m) * OUT2 + c2) = h;
      }
      slo += zlo; shi += zhi;
      qlo = fmaf(zlo, zlo, qlo);
      qhi = fmaf(zhi, zhi, qhi);
    }
  }
  atomicAdd(&lsum[c2], slo);     atomicAdd(&lsum[c2 + 1], shi);
  atomicAdd(&lsumsq[c2], qlo);   atomicAdd(&lsumsq[c2 + 1], qhi);
  __syncthreads();
  if (tid < OUT2) {
    atomicAdd(&gsum[tid], lsum[tid]);
    atomicAdd(&gsumsq[tid], lsumsq[tid]);
  }
}

// ---------------- fallback-path machinery (ws too small; r5 structure) ----------------
__device__ __forceinline__ void edge_gemm(
    const _Float16* snf, const float* sW, int ebase, int c0,
    float4 acc0[6], float4 acc1[6]) {
#pragma unroll
  for (int e = 0; e < 6; ++e) { acc0[e] = zero4(); acc1[e] = zero4(); }
  for (int k0 = 0; k0 < 40; k0 += 4) {
    h4 av[6];
#pragma unroll
    for (int e = 0; e < 6; ++e)
      av[e] = *(const h4*)(snf + (ebase + e) * NF_STRIDE + k0);
#pragma unroll
    for (int kk = 0; kk < 4; ++kk) {
      float4 b0 = *(const float4*)(sW + (k0 + kk) * OUT2 + c0);
      float4 b1 = *(const float4*)(sW + (k0 + kk) * OUT2 + AF + c0);
#pragma unroll
      for (int e = 0; e < 6; ++e) {
        float s = (float)av[e][kk];
        fma4(acc0[e], s, b0);
        fma4(acc1[e], s, b1);
      }
    }
  }
  {
    float4 b0 = *(const float4*)(sW + 40 * OUT2 + c0);
    float4 b1 = *(const float4*)(sW + 40 * OUT2 + AF + c0);
#pragma unroll
    for (int e = 0; e < 6; ++e) {
      float s = (float)snf[(ebase + e) * NF_STRIDE + 40];
      fma4(acc0[e], s, b0);
      fma4(acc1[e], s, b1);
    }
  }
}

__device__ __forceinline__ void stage_edge(
    const float* __restrict__ nbr_fea, const int* __restrict__ nidx,
    const float* __restrict__ We, int a0, int tid,
    _Float16* snf, float* sW, int* sidx) {
  float4* sW4 = (float4*)sW;
  const float4* gW4 = (const float4*)We;
  for (int e = tid; e < NBR_FEA * (OUT2 / 4); e += 256) sW4[e] = gW4[e];
  const float* gnf = nbr_fea + (size_t)a0 * M_NBR * NBR_FEA;
  for (int e = tid; e < EDGES * NBR_FEA; e += 256) {
    int r = e / NBR_FEA;
    int k = e - r * NBR_FEA;
    snf[r * NF_STRIDE + k] = (_Float16)gnf[e];
  }
  for (int e = tid; e < EDGES; e += 256) {
    snf[e * NF_STRIDE + 41] = (_Float16)0.f;
    snf[e * NF_STRIDE + 42] = (_Float16)0.f;
    snf[e * NF_STRIDE + 43] = (_Float16)0.f;
    sidx[e] = nidx[(size_t)a0 * M_NBR + e];
  }
}

__global__ __launch_bounds__(256, 2) void k_zstats_fb(
    const float* __restrict__ nbr_fea, const int* __restrict__ nidx,
    const float* __restrict__ y_self, const float* __restrict__ y_nbr,
    const float* __restrict__ Wf, const float* __restrict__ bf,
    float* __restrict__ gsum, float* __restrict__ gsumsq) {
  __shared__ __align__(16) _Float16 snf[EDGES * NF_STRIDE];
  __shared__ __align__(16) float sW[NBR_FEA * OUT2];
  __shared__ int sidx[EDGES];
  __shared__ float lsum[OUT2], lsumsq[OUT2];
  int tid = threadIdx.x;
  int cg = tid & 15, eg = tid >> 4;
  int c0 = cg * 4;
  if (tid < OUT2) { lsum[tid] = 0.f; lsumsq[tid] = 0.f; }
  int a0 = blockIdx.x * ZCH;
  stage_edge(nbr_fea, nidx, Wf + 2 * AF * OUT2, a0, tid, snf, sW, sidx);
  __syncthreads();
  float4 bz0 = *(const float4*)(bf + c0);
  float4 bz1 = *(const float4*)(bf + AF + c0);
  float4 sm0 = zero4(), sq0 = zero4(), sm1 = zero4(), sq1 = zero4();
  for (int c = 0; c < 2; ++c) {
    int ebase = c * 96 + eg * 6;
    int atomL = c * 8 + (eg >> 1);
    const float* ys = y_self + (size_t)(a0 + atomL) * OUT2;
    float4 y0 = *(const float4*)(ys + c0);
    float4 y1 = *(const float4*)(ys + AF + c0);
    float4 acc0[6], acc1[6];
    edge_gemm(snf, sW, ebase, c0, acc0, acc1);
#pragma unroll
    for (int e = 0; e < 6; ++e) {
      int j = sidx[ebase + e];
      const float* yn = y_nbr + (size_t)j * OUT2;
      float4 n0 = *(const float4*)(yn + c0);
      float4 n1 = *(const float4*)(yn + AF + c0);
      float4 z0, z1;
      z0.x = acc0[e].x + y0.x + n0.x + bz0.x; z0.y = acc0[e].y + y0.y + n0.y + bz0.y;
      z0.z = acc0[e].z + y0.z + n0.z + bz0.z; z0.w = acc0[e].w + y0.w + n0.w + bz0.w;
      z1.x = acc1[e].x + y1.x + n1.x + bz1.x; z1.y = acc1[e].y + y1.y + n1.y + bz1.y;
      z1.z = acc1[e].z + y1.z + n1.z + bz1.z; z1.w = acc1[e].w + y1.w + n1.w + bz1.w;
      sm0.x += z0.x; sm0.y += z0.y; sm0.z += z0.z; sm0.w += z0.w;
      sm1.x += z1.x; sm1.y += z1.y; sm1.z += z1.z; sm1.w += z1.w;
      sq0.x = fmaf(z0.x, z0.x, sq0.x); sq0.y = fmaf(z0.y, z0.y, sq0.y);
      sq0.z = fmaf(z0.z, z0.z, sq0.z); sq0.w = fmaf(z0.w, z0.w, sq0.w);
      sq1.x = fmaf(z1.x, z1.x, sq1.x); sq1.y = fmaf(z1.y, z1.y, sq1.y);
      sq1.z = fmaf(z1.z, z1.z, sq1.z); sq1.w = fmaf(z1.w, z1.w, sq1.w);
    }
  }
  atomicAdd(&lsum[c0 + 0], sm0.x); atomicAdd(&lsum[c0 + 1], sm0.y);
  atomicAdd(&lsum[c0 + 2], sm0.z); atomicAdd(&lsum[c0 + 3], sm0.w);
  atomicAdd(&lsum[AF + c0 + 0], sm1.x); atomicAdd(&lsum[AF + c0 + 1], sm1.y);
  atomicAdd(&lsum[AF + c0 + 2], sm1.z); atomicAdd(&lsum[AF + c0 + 3], sm1.w);
  atomicAdd(&lsumsq[c0 + 0], sq0.x); atomicAdd(&lsumsq[c0 + 1], sq0.y);
  atomicAdd(&lsumsq[c0 + 2], sq0.z); atomicAdd(&lsumsq[c0 + 3], sq0.w);
  atomicAdd(&lsumsq[AF + c0 + 0], sq1.x); atomicAdd(&lsumsq[AF + c0 + 1], sq1.y);
  atomicAdd(&lsumsq[AF + c0 + 2], sq1.z); atomicAdd(&lsumsq[AF + c0 + 3], sq1.w);
  __syncthreads();
  if (tid < OUT2) {
    atomicAdd(&gsum[tid], lsum[tid]);
    atomicAdd(&gsumsq[tid], lsumsq[tid]);
  }
}

// Pass 2 FAST PATH: pure stream over persisted z16.
__global__ __launch_bounds__(256, 4) void k_apply_stream(
    const __half* __restrict__ z16,
    const float* __restrict__ sc1, const float* __restrict__ sh1,
    float* __restrict__ s_out, float* __restrict__ gsum, float* __restrict__ gsumsq) {
  __shared__ float lsum[AF], lsumsq[AF];
  int tid = threadIdx.x;
  if (tid < AF) { lsum[tid] = 0.f; lsumsq[tid] = 0.f; }
  __syncthreads();
  int cg = tid & 15, a = tid >> 4;     // 16 atoms per block
  int c0 = cg * 4;
  size_t atom = (size_t)blockIdx.x * 16 + a;
  float4 f0 = *(const float4*)(sc1 + c0);
  float4 g0 = *(const float4*)(sh1 + c0);
  float4 f1 = *(const float4*)(sc1 + AF + c0);
  float4 g1 = *(const float4*)(sh1 + AF + c0);
  const __half* zr = z16 + atom * (M_NBR * OUT2);
  float4 sacc = zero4();
#pragma unroll 4
  for (int m = 0; m < M_NBR; ++m) {
    float4 zf = load_h4(zr + m * OUT2 + c0);
    float4 zc = load_h4(zr + m * OUT2 + AF + c0);
    zf.x = fmaf(zf.x, f0.x, g0.x); zf.y = fmaf(zf.y, f0.y, g0.y);
    zf.z = fmaf(zf.z, f0.z, g0.z); zf.w = fmaf(zf.w, f0.w, g0.w);
    zc.x = fmaf(zc.x, f1.x, g1.x); zc.y = fmaf(zc.y, f1.y, g1.y);
    zc.z = fmaf(zc.z, f1.z, g1.z); zc.w = fmaf(zc.w, f1.w, g1.w);
    sacc.x = fmaf(sigmoid_f(zf.x), softplus_f(zc.x), sacc.x);
    sacc.y = fmaf(sigmoid_f(zf.y), softplus_f(zc.y), sacc.y);
    sacc.z = fmaf(sigmoid_f(zf.z), softplus_f(zc.z), sacc.z);
    sacc.w = fmaf(sigmoid_f(zf.w), softplus_f(zc.w), sacc.w);
  }
  *(float4*)(s_out + atom * AF + c0) = sacc;
  float4 sq;
  sq.x = sacc.x * sacc.x; sq.y = sacc.y * sacc.y;
  sq.z = sacc.z * sacc.z; sq.w = sacc.w * sacc.w;
  sacc.x += __shfl_xor(sacc.x, 16, 64); sacc.y += __shfl_xor(sacc.y, 16, 64);
  sacc.z += __shfl_xor(sacc.z, 16, 64); sacc.w += __shfl_xor(sacc.w, 16, 64);
  sq.x += __shfl_xor(sq.x, 16, 64); sq.y += __shfl_xor(sq.y, 16, 64);
  sq.z += __shfl_xor(sq.z, 16, 64); sq.w += __shfl_xor(sq.w, 16, 64);
  sacc.x += __shfl_xor(sacc.x, 32, 64); sacc.y += __shfl_xor(sacc.y, 32, 64);
  sacc.z += __shfl_xor(sacc.z, 32, 64); sacc.w += __shfl_xor(sacc.w, 32, 64);
  sq.x += __shfl_xor(sq.x, 32, 64); sq.y += __shfl_xor(sq.y, 32, 64);
  sq.z += __shfl_xor(sq.z, 32, 64); sq.w += __shfl_xor(sq.w, 32, 64);
  if ((tid & 48) == 0) {
    atomicAdd(&lsum[c0 + 0], sacc.x); atomicAdd(&lsum[c0 + 1], sacc.y);
    atomicAdd(&lsum[c0 + 2], sacc.z); atomicAdd(&lsum[c0 + 3], sacc.w);
    atomicAdd(&lsumsq[c0 + 0], sq.x); atomicAdd(&lsumsq[c0 + 1], sq.y);
    atomicAdd(&lsumsq[c0 + 2], sq.z); atomicAdd(&lsumsq[c0 + 3], sq.w);
  }
  __syncthreads();
  if (tid < AF) {
    atomicAdd(&gsum[tid], lsum[tid]);
    atomicAdd(&gsumsq[tid], lsumsq[tid]);
  }
}

// Pass 2 FALLBACK (ws too small): recompute z.
__global__ __launch_bounds__(256, 2) void k_apply(
    const float* __restrict__ nbr_fea, const int* __restrict__ nidx,
    const float* __restrict__ y_self, const float* __restrict__ y_nbr,
    const float* __restrict__ Wf, const float* __restrict__ bf,
    const float* __restrict__ sc1, const float* __restrict__ sh1,
    float* __restrict__ s_out, float* __restrict__ gsum, float* __restrict__ gsumsq) {
  __shared__ __align__(16) _Float16 snf[EDGES * NF_STRIDE];
  __shared__ __align__(16) float sW[NBR_FEA * OUT2];
  __shared__ int sidx[EDGES];
  __shared__ float lsum[AF], lsumsq[AF];
  int tid = threadIdx.x;
  int cg = tid & 15, eg = tid >> 4;
  int c0 = cg * 4;
  if (tid < AF) { lsum[tid] = 0.f; lsumsq[tid] = 0.f; }
  int a0 = blockIdx.x * ZCH;
  stage_edge(nbr_fea, nidx, Wf + 2 * AF * OUT2, a0, tid, snf, sW, sidx);
  __syncthreads();
  float4 bz0 = *(const float4*)(bf + c0);
  float4 bz1 = *(const float4*)(bf + AF + c0);
  float4 f0 = *(const float4*)(sc1 + c0);
  float4 g0 = *(const float4*)(sh1 + c0);
  float4 f1 = *(const float4*)(sc1 + AF + c0);
  float4 g1 = *(const float4*)(sh1 + AF + c0);
  for (int c = 0; c < 2; ++c) {
    int ebase = c * 96 + eg * 6;
    int atomL = c * 8 + (eg >> 1);
    const float* ys = y_self + (size_t)(a0 + atomL) * OUT2;
    float4 y0 = *(const float4*)(ys + c0);
    float4 y1 = *(const float4*)(ys + AF + c0);
    float4 acc0[6], acc1[6];
    edge_gemm(snf, sW, ebase, c0, acc0, acc1);
    float4 sacc = zero4();
#pragma unroll
    for (int e = 0; e < 6; ++e) {
      int j = sidx[ebase + e];
      const float* yn = y_nbr + (size_t)j * OUT2;
      float4 n0 = *(const float4*)(yn + c0);
      float4 n1 = *(const float4*)(yn + AF + c0);
      float4 z0, z1;
      z0.x = fmaf(acc0[e].x + y0.x + n0.x + bz0.x, f0.x, g0.x);
      z0.y = fmaf(acc0[e].y + y0.y + n0.y + bz0.y, f0.y, g0.y);
      z0.z = fmaf(acc0[e].z + y0.z + n0.z + bz0.z, f0.z, g0.z);
      z0.w = fmaf(acc0[e].w + y0.w + n0.w + bz0.w, f0.w, g0.w);
      z1.x = fmaf(acc1[e].x + y1.x + n1.x + bz1.x, f1.x, g1.x);
      z1.y = fmaf(acc1[e].y + y1.y + n1.y + bz1.y, f1.y, g1.y);
      z1.z = fmaf(acc1[e].z + y1.z + n1.z + bz1.z, f1.z, g1.z);
      z1.w = fmaf(acc1[e].w + y1.w + n1.w + bz1.w, f1.w, g1.w);
      sacc.x = fmaf(sigmoid_f(z0.x), softplus_f(z1.x), sacc.x);
      sacc.y = fmaf(sigmoid_f(z0.y), softplus_f(z1.y), sacc.y);
      sacc.z = fmaf(sigmoid_f(z0.z), softplus_f(z1.z), sacc.z);
      sacc.w = fmaf(sigmoid_f(z0.w), softplus_f(z1.w), sacc.w);
    }
    sacc.x += __shfl_xor(sacc.x, 16, 64);
    sacc.y += __shfl_xor(sacc.y, 16, 64);
    sacc.z += __shfl_xor(sacc.z, 16, 64);
    sacc.w += __shfl_xor(sacc.w, 16, 64);
    if ((eg & 1) == 0) {
      *(float4*)(s_out + (size_t)(a0 + atomL) * AF + c0) = sacc;
      atomicAdd(&lsum[c0 + 0], sacc.x); atomicAdd(&lsum[c0 + 1], sacc.y);
      atomicAdd(&lsum[c0 + 2], sacc.z); atomicAdd(&lsum[c0 + 3], sacc.w);
      atomicAdd(&lsumsq[c0 + 0], sacc.x * sacc.x);
      atomicAdd(&lsumsq[c0 + 1], sacc.y * sacc.y);
      atomicAdd(&lsumsq[c0 + 2], sacc.z * sacc.z);
      atomicAdd(&lsumsq[c0 + 3], sacc.w * sacc.w);
    }
  }
  __syncthreads();
  if (tid < AF) {
    atomicAdd(&gsum[tid], lsum[tid]);
    atomicAdd(&gsumsq[tid], lsumsq[tid]);
  }
}

__global__ void k_finalize(const float* __restrict__ gsum, const float* __restrict__ gsumsq,
                           const float* __restrict__ gamma, const float* __restrict__ beta,
                           float* __restrict__ scale, float* __restrict__ shift,
                           int chn, float invcount) {
  int c = threadIdx.x;
  if (c < chn) {
    float m = gsum[c] * invcount;
    float v = gsumsq[c] * invcount - m * m;
    float sc = gamma[c] * rsqrtf(v + EPS);
    scale[c] = sc;
    shift[c] = beta[c] - m * sc;
  }
}

__global__ __launch_bounds__(256) void k_update(
    float* __restrict__ x, const float* __restrict__ s,
    const float* __restrict__ sc2, const float* __restrict__ sh2) {
  int e = blockIdx.x * 256 + threadIdx.x;
  if (e < N_ATOMS * AF) {
    int c = e & (AF - 1);
    float v = x[e] + s[e] * sc2[c] + sh2[c];
    x[e] = softplus_f(v);
  }
}

__global__ __launch_bounds__(128) void k_pool(
    const float* __restrict__ x, const int* __restrict__ cidx,
    const float* __restrict__ Wp, const float* __restrict__ bp,
    float* __restrict__ out) {
  __shared__ float part[2][AF];
  __shared__ float mean[AF];
  int g = blockIdx.x, tid = threadIdx.x;
  int c = tid & 63, h = tid >> 6;
  float acc = 0.f;
  for (int a = h; a < ATOMS_PER; a += 2) {
    int idx = cidx[g * ATOMS_PER + a];
    acc += x[(size_t)idx * AF + c];
  }
  part[h][c] = acc;
  __syncthreads();
  if (tid < AF) mean[tid] = (part[0][tid] + part[1][tid]) * (1.0f / ATOMS_PER);
  __syncthreads();
  float o = bp[tid];
#pragma unroll
  for (int k = 0; k < AF; ++k) o += mean[k] * Wp[k * OUT_DIM + tid];
  out[(size_t)g * OUT_DIM + tid] = fmaxf(o, 0.f);
}

extern "C" void kernel_launch(void* const* d_in, const int* in_sizes, int n_in,
                              void* d_out, int out_size, void* d_ws, size_t ws_size,
                              hipStream_t stream) {
  const float* atom_fea = (const float*)d_in[0];
  const float* nbr_fea  = (const float*)d_in[1];
  const int*   nbr_idx  = (const int*)d_in[2];
  const int*   cidx     = (const int*)d_in[3];
  const float* W_embed  = (const float*)d_in[4];
  const float* b_embed  = (const float*)d_in[5];
  const float* W_full   = (const float*)d_in[6];
  const float* b_full   = (const float*)d_in[7];
  const float* bn1_g    = (const float*)d_in[8];
  const float* bn1_b    = (const float*)d_in[9];
  const float* bn2_g    = (const float*)d_in[10];
  const float* bn2_b    = (const float*)d_in[11];
  const float* W_pool   = (const float*)d_in[12];
  const float* b_pool   = (const float*)d_in[13];
  float* out = (float*)d_out;

  float* ws = (float*)d_ws;
  size_t off = 0;
  float* x      = ws + off; off += (size_t)N_ATOMS * AF;
  float* y_self = ws + off; off += (size_t)N_ATOMS * OUT2;
  float* y_nbr  = ws + off; off += (size_t)N_ATOMS * OUT2;
  float* s_buf  = ws + off; off += (size_t)N_ATOMS * AF;
  float* sums   = ws + off; off += (size_t)N_CONV * 384;   // sum1/sumsq1/sum2/sumsq2
  float* affine = ws + off; off += (size_t)N_CONV * 384;   // sc1/sh1/sc2/sh2

  size_t base_bytes = (off * sizeof(float) + 255) & ~(size_t)255;  // 256B align z16
  size_t z_bytes = (size_t)N_ATOMS * M_NBR * OUT2 * sizeof(__half);   // 307.2 MB
  bool fast = ws_size >= base_bytes + z_bytes;
  __half* z16 = fast ? (__half*)((char*)d_ws + base_bytes) : nullptr;

  hipMemsetAsync(sums, 0, (size_t)N_CONV * 384 * sizeof(float), stream);

  k_embed<<<(N_ATOMS + 63) / 64, 256, 0, stream>>>(atom_fea, W_embed, b_embed, x);

  for (int i = 0; i < N_CONV; ++i) {
    const float* Wf = W_full + (size_t)i * IN_FULL * OUT2;
    const float* bf = b_full + (size_t)i * OUT2;
    float* sum1   = sums + (size_t)i * 384;
    float* sumsq1 = sum1 + OUT2;
    float* sum2   = sumsq1 + OUT2;
    float* sumsq2 = sum2 + AF;
    float* sc1 = affine + (size_t)i * 384;
    float* sh1 = sc1 + OUT2;
    float* sc2 = sh1 + OUT2;
    float* sh2 = sc2 + AF;

    k_ysn<<<N_ATOMS / YB_ATOMS, 256, 0, stream>>>(x, Wf, y_self, y_nbr);
    if (fast) {
      k_zstats_w<1><<<ZW_BLOCKS, 256, 0, stream>>>(
          nbr_fea, nbr_idx, y_self, y_nbr, Wf, bf, sum1, sumsq1, z16);
    } else {
      k_zstats_fb<<<N_ATOMS / ZCH, 256, 0, stream>>>(
          nbr_fea, nbr_idx, y_self, y_nbr, Wf, bf, sum1, sumsq1);
    }
    k_finalize<<<1, 128, 0, stream>>>(sum1, sumsq1, bn1_g + i * OUT2, bn1_b + i * OUT2,
                                      sc1, sh1, OUT2, 1.0f / ((float)N_ATOMS * M_NBR));
    if (fast) {
      k_apply_stream<<<N_ATOMS / 16, 256, 0, stream>>>(z16, sc1, sh1, s_buf,
                                                       sum2, sumsq2);
    } else {
      k_apply<<<N_ATOMS / ZCH, 256, 0, stream>>>(nbr_fea, nbr_idx, y_self, y_nbr,
                                                 Wf, bf, sc1, sh1, s_buf, sum2, sumsq2);
    }
    k_finalize<<<1, 128, 0, stream>>>(sum2, sumsq2, bn2_g + i * AF, bn2_b + i * AF,
                                      sc2, sh2, AF, 1.0f / (float)N_ATOMS);
    k_update<<<(N_ATOMS * AF + 255) / 256, 256, 0, stream>>>(x, s_buf, sc2, sh2);
  }

  k_pool<<<N_CRYSTALS, 128, 0, stream>>>(x, cidx, W_pool, b_pool, out);
}

// Round 8
// 1967.408 us; speedup vs baseline: 1.2567x; 1.2567x over previous
//
#include <hip/hip_runtime.h>
#include <hip/hip_fp16.h>
#include <math.h>

#define N_ATOMS 100000
#define M_NBR 12
#define ORIG_FEA 92
#define NBR_FEA 41
#define AF 64
#define OUT2 128          // 2*AF
#define IN_FULL 169       // 2*AF + NBR_FEA
#define N_CONV 3
#define OUT_DIM 128
#define N_CRYSTALS 2000
#define ATOMS_PER 50
#define EPS 1e-5f

#define ZCH 16            // atoms per chunk (100000 % 16 == 0)
#define EDGES (ZCH * M_NBR)          // 192
#define NF_STRIDE 44      // padded fp16 row stride (8B-aligned)
#define YB_ATOMS 80       // atoms per ysn block (100000 % 80 == 0)
#define YB_CHUNK 16
#define ZP_BLOCKS 1024    // persistent zstats grid: exactly 4 blocks/CU

typedef _Float16 h4 __attribute__((ext_vector_type(4)));

// cheap softplus: log1p(t)->log(1+t) adds only ~2^-24 abs error (result feeds sums)
__device__ __forceinline__ float softplus_f(float x) {
    return fmaxf(x, 0.0f) + __logf(1.0f + __expf(-fabsf(x)));
}
__device__ __forceinline__ float sigmoid_f(float x) {
    return __builtin_amdgcn_rcpf(1.0f + __expf(-x));   // v_rcp_f32, ~1ulp
}
__device__ __forceinline__ void fma4(float4& a, float s, const float4& b) {
    a.x = fmaf(s, b.x, a.x); a.y = fmaf(s, b.y, a.y);
    a.z = fmaf(s, b.z, a.z); a.w = fmaf(s, b.w, a.w);
}
__device__ __forceinline__ float4 zero4() { return make_float4(0.f, 0.f, 0.f, 0.f); }

union H4 { uint2 u; __half2 h[2]; };
__device__ __forceinline__ void store_h4(__half* p, float4 v) {
    H4 t;
    t.h[0] = __floats2half2_rn(v.x, v.y);
    t.h[1] = __floats2half2_rn(v.z, v.w);
    *(uint2*)p = t.u;
}
__device__ __forceinline__ float4 load_h4(const __half* p) {
    H4 t; t.u = *(const uint2*)p;
    float2 a = __half22float2(t.h[0]);
    float2 b = __half22float2(t.h[1]);
    return make_float4(a.x, a.y, b.x, b.y);
}

// x[n][c] = b[c] + sum_k af[n][k]*W[k][c]   (c<64, k<92)
__global__ __launch_bounds__(256, 2) void k_embed(
    const float* __restrict__ af, const float* __restrict__ W,
    const float* __restrict__ b, float* __restrict__ x) {
  __shared__ __align__(16) float saf[64 * ORIG_FEA];
  int a0 = blockIdx.x * 64;
  int na = min(64, N_ATOMS - a0);
  int tid = threadIdx.x;
  int c = tid & 63, rgrp = tid >> 6;
  float w[ORIG_FEA];
#pragma unroll
  for (int k = 0; k < ORIG_FEA; ++k) w[k] = W[k * AF + c];
  int n4 = na * (ORIG_FEA / 4);
  const float4* g4 = (const float4*)(af + (size_t)a0 * ORIG_FEA);
  float4* s4 = (float4*)saf;
  for (int e = tid; e < n4; e += 256) s4[e] = g4[e];
  __syncthreads();
  float bc = b[c];
  for (int a = rgrp; a < na; a += 4) {
    float acc = bc;
    const float4* row = (const float4*)(saf + a * ORIG_FEA);
#pragma unroll
    for (int q = 0; q < ORIG_FEA / 4; ++q) {
      float4 v = row[q];
      acc = fmaf(v.x, w[4 * q], acc);
      acc = fmaf(v.y, w[4 * q + 1], acc);
      acc = fmaf(v.z, w[4 * q + 2], acc);
      acc = fmaf(v.w, w[4 * q + 3], acc);
    }
    x[(size_t)(a0 + a) * AF + c] = acc;
  }
}

// y GEMM: [100k x 64] @ [64 x 256] -> y_self[n][128], y_nbr[n][128].
__global__ __launch_bounds__(256, 2) void k_ysn(
    const float* __restrict__ x, const float* __restrict__ Wf,
    float* __restrict__ y_self, float* __restrict__ y_nbr) {
  __shared__ __align__(16) float sW2[64 * 256];
  __shared__ __align__(16) float sx[YB_CHUNK * AF];
  int tid = threadIdx.x;
  int cg = tid & 31, ag = tid >> 5;     // cg: ch-quad, ag: atom-pair
  int c0 = cg * 4;
  {  // stage W': cols 0..127 = Wf[0:64][:], cols 128..255 = Wf[64:128][:]
    float4* s4 = (float4*)sW2;
    const float4* g4 = (const float4*)Wf;
    for (int e = tid; e < 64 * 64; e += 256) {
      int r = e >> 6, q = e & 63;
      s4[r * 64 + q] = (q < 32) ? g4[r * 32 + q] : g4[(64 + r) * 32 + (q - 32)];
    }
  }
  int ab = blockIdx.x * YB_ATOMS;
  for (int cc = 0; cc < YB_ATOMS / YB_CHUNK; ++cc) {
    int a0 = ab + cc * YB_CHUNK;
    __syncthreads();
    {
      float4* s4 = (float4*)sx;
      const float4* g4 = (const float4*)(x + (size_t)a0 * AF);
      for (int e = tid; e < YB_CHUNK * AF / 4; e += 256) s4[e] = g4[e];
    }
    __syncthreads();
    float4 accs[2] = {zero4(), zero4()};
    float4 accn[2] = {zero4(), zero4()};
    for (int k0 = 0; k0 < AF; k0 += 4) {
      float4 av0 = *(const float4*)(sx + (ag * 2 + 0) * AF + k0);
      float4 av1 = *(const float4*)(sx + (ag * 2 + 1) * AF + k0);
#pragma unroll
      for (int kk = 0; kk < 4; ++kk) {
        float4 b0 = *(const float4*)(sW2 + (k0 + kk) * 256 + c0);
        float4 b1 = *(const float4*)(sW2 + (k0 + kk) * 256 + 128 + c0);
        float s0 = (kk == 0) ? av0.x : (kk == 1) ? av0.y : (kk == 2) ? av0.z : av0.w;
        float s1 = (kk == 0) ? av1.x : (kk == 1) ? av1.y : (kk == 2) ? av1.z : av1.w;
        fma4(accs[0], s0, b0); fma4(accn[0], s0, b1);
        fma4(accs[1], s1, b0); fma4(accn[1], s1, b1);
      }
    }
#pragma unroll
    for (int t = 0; t < 2; ++t) {
      size_t n = (size_t)(a0 + ag * 2 + t);
      *(float4*)(y_self + n * OUT2 + c0) = accs[t];
      *(float4*)(y_nbr + n * OUT2 + c0) = accn[t];
    }
  }
}

// Edge GEMM micro-kernel: A fp16 from LDS (cvt at use), B f32 from LDS, f32 FMA.
// Each LDS read of b0/b1 is reused by 6 edges (key LDS-BW amortization).
__device__ __forceinline__ void edge_gemm(
    const _Float16* snf, const float* sW, int ebase, int c0,
    float4 acc0[6], float4 acc1[6]) {
#pragma unroll
  for (int e = 0; e < 6; ++e) { acc0[e] = zero4(); acc1[e] = zero4(); }
  for (int k0 = 0; k0 < 40; k0 += 4) {
    h4 av[6];
#pragma unroll
    for (int e = 0; e < 6; ++e)
      av[e] = *(const h4*)(snf + (ebase + e) * NF_STRIDE + k0);
#pragma unroll
    for (int kk = 0; kk < 4; ++kk) {
      float4 b0 = *(const float4*)(sW + (k0 + kk) * OUT2 + c0);
      float4 b1 = *(const float4*)(sW + (k0 + kk) * OUT2 + AF + c0);
#pragma unroll
      for (int e = 0; e < 6; ++e) {
        float s = (float)av[e][kk];
        fma4(acc0[e], s, b0);
        fma4(acc1[e], s, b1);
      }
    }
  }
  {  // k = 40 tail
    float4 b0 = *(const float4*)(sW + 40 * OUT2 + c0);
    float4 b1 = *(const float4*)(sW + 40 * OUT2 + AF + c0);
#pragma unroll
    for (int e = 0; e < 6; ++e) {
      float s = (float)snf[(ebase + e) * NF_STRIDE + 40];
      fma4(acc0[e], s, b0);
      fma4(acc1[e], s, b1);
    }
  }
}

// ---------------- FAST PATH pass 1: PERSISTENT blocks ----------------
// r1-r5 lesson: the 21KB W-stage repeated per 16-atom block (6250x = 131MB HBM +
// barrier) was the fixed-cost wall. r6/r7: register-resident W is un-coercible
// (compiler pins VGPR=56-60). So: 1024 persistent blocks (exactly 4/CU), W staged
// ONCE per block, grid-stride over 16-atom chunks staging only the 16.9KB fp16 snf.
// Stats live in registers across chunks; one reduce per block.
// LDS = 16896 + 21504 + 1024(sidx/reduce alias) = 39424 B exactly — r4 measured
// 44.9% occupancy at this size; 39936 (r5) fell to 22%. Do not grow this.
template <int WZ>
__global__ __launch_bounds__(256, 2) void k_zstats_p(
    const float* __restrict__ nbr_fea, const int* __restrict__ nidx,
    const float* __restrict__ y_self, const float* __restrict__ y_nbr,
    const float* __restrict__ Wf, const float* __restrict__ bf,
    float* __restrict__ gsum, float* __restrict__ gsumsq,
    __half* __restrict__ z16) {
  __shared__ __align__(16) _Float16 snf[EDGES * NF_STRIDE];   // 16896 B
  __shared__ __align__(16) float sW[NBR_FEA * OUT2];          // 21504 B
  __shared__ __align__(16) unsigned char sbuf[1024];          // sidx (loop) / lsum|lsumsq (end)
  int* sidx = (int*)sbuf;                                     // 768 B used
  int tid = threadIdx.x;
  int cg = tid & 15, eg = tid >> 4;
  int c0 = cg * 4;
  {  // stage W once per (persistent) block
    float4* sW4 = (float4*)sW;
    const float4* gW4 = (const float4*)(Wf + 2 * AF * OUT2);
    for (int e = tid; e < NBR_FEA * (OUT2 / 4); e += 256) sW4[e] = gW4[e];
  }
  float4 bz0 = *(const float4*)(bf + c0);
  float4 bz1 = *(const float4*)(bf + AF + c0);
  float4 sm0 = zero4(), sq0 = zero4(), sm1 = zero4(), sq1 = zero4();
  for (int cc = blockIdx.x; cc < N_ATOMS / ZCH; cc += ZP_BLOCKS) {
    int a0 = cc * ZCH;
    __syncthreads();   // prior chunk's reads done (and W visible on first iter)
    const float* gnf = nbr_fea + (size_t)a0 * M_NBR * NBR_FEA;
    for (int e = tid; e < EDGES * NBR_FEA; e += 256) {
      int r = e / NBR_FEA;
      int k = e - r * NBR_FEA;
      snf[r * NF_STRIDE + k] = (_Float16)gnf[e];
    }
    for (int e = tid; e < EDGES; e += 256) {
      snf[e * NF_STRIDE + 41] = (_Float16)0.f;
      snf[e * NF_STRIDE + 42] = (_Float16)0.f;
      snf[e * NF_STRIDE + 43] = (_Float16)0.f;
      sidx[e] = nidx[(size_t)a0 * M_NBR + e];
    }
    __syncthreads();
    for (int c = 0; c < 2; ++c) {
      int ebase = c * 96 + eg * 6;
      int atomL = c * 8 + (eg >> 1);
      const float* ys = y_self + (size_t)(a0 + atomL) * OUT2;
      float4 y0 = *(const float4*)(ys + c0);
      float4 y1 = *(const float4*)(ys + AF + c0);
      float4 acc0[6], acc1[6];
      edge_gemm(snf, sW, ebase, c0, acc0, acc1);
#pragma unroll
      for (int e = 0; e < 6; ++e) {
        int j = sidx[ebase + e];
        const float* yn = y_nbr + (size_t)j * OUT2;
        float4 n0 = *(const float4*)(yn + c0);
        float4 n1 = *(const float4*)(yn + AF + c0);
        float4 z0, z1;
        z0.x = acc0[e].x + y0.x + n0.x + bz0.x; z0.y = acc0[e].y + y0.y + n0.y + bz0.y;
        z0.z = acc0[e].z + y0.z + n0.z + bz0.z; z0.w = acc0[e].w + y0.w + n0.w + bz0.w;
        z1.x = acc1[e].x + y1.x + n1.x + bz1.x; z1.y = acc1[e].y + y1.y + n1.y + bz1.y;
        z1.z = acc1[e].z + y1.z + n1.z + bz1.z; z1.w = acc1[e].w + y1.w + n1.w + bz1.w;
        if (WZ) {
          __half* zp = z16 + ((size_t)a0 * M_NBR + ebase + e) * OUT2 + c0;
          store_h4(zp, z0);
          store_h4(zp + AF, z1);
        }
        sm0.x += z0.x; sm0.y += z0.y; sm0.z += z0.z; sm0.w += z0.w;
        sm1.x += z1.x; sm1.y += z1.y; sm1.z += z1.z; sm1.w += z1.w;
        sq0.x = fmaf(z0.x, z0.x, sq0.x); sq0.y = fmaf(z0.y, z0.y, sq0.y);
        sq0.z = fmaf(z0.z, z0.z, sq0.z); sq0.w = fmaf(z0.w, z0.w, sq0.w);
        sq1.x = fmaf(z1.x, z1.x, sq1.x); sq1.y = fmaf(z1.y, z1.y, sq1.y);
        sq1.z = fmaf(z1.z, z1.z, sq1.z); sq1.w = fmaf(z1.w, z1.w, sq1.w);
      }
    }
  }
  // ---- once-per-block reduce (sidx no longer needed; reuse sbuf) ----
  __syncthreads();
  float* lsum = (float*)sbuf;          // [OUT2]
  float* lsumsq = lsum + OUT2;         // [OUT2]
  ((float*)sbuf)[tid] = 0.f;           // 256 threads zero 256 floats = 1024 B
  __syncthreads();
  atomicAdd(&lsum[c0 + 0], sm0.x); atomicAdd(&lsum[c0 + 1], sm0.y);
  atomicAdd(&lsum[c0 + 2], sm0.z); atomicAdd(&lsum[c0 + 3], sm0.w);
  atomicAdd(&lsum[AF + c0 + 0], sm1.x); atomicAdd(&lsum[AF + c0 + 1], sm1.y);
  atomicAdd(&lsum[AF + c0 + 2], sm1.z); atomicAdd(&lsum[AF + c0 + 3], sm1.w);
  atomicAdd(&lsumsq[c0 + 0], sq0.x); atomicAdd(&lsumsq[c0 + 1], sq0.y);
  atomicAdd(&lsumsq[c0 + 2], sq0.z); atomicAdd(&lsumsq[c0 + 3], sq0.w);
  atomicAdd(&lsumsq[AF + c0 + 0], sq1.x); atomicAdd(&lsumsq[AF + c0 + 1], sq1.y);
  atomicAdd(&lsumsq[AF + c0 + 2], sq1.z); atomicAdd(&lsumsq[AF + c0 + 3], sq1.w);
  __syncthreads();
  if (tid < OUT2) {
    atomicAdd(&gsum[tid], lsum[tid]);
    atomicAdd(&gsumsq[tid], lsumsq[tid]);
  }
}

// ---------------- fallback-path machinery (ws too small) ----------------
__device__ __forceinline__ void stage_edge(
    const float* __restrict__ nbr_fea, const int* __restrict__ nidx,
    const float* __restrict__ We, int a0, int tid,
    _Float16* snf, float* sW, int* sidx) {
  float4* sW4 = (float4*)sW;
  const float4* gW4 = (const float4*)We;
  for (int e = tid; e < NBR_FEA * (OUT2 / 4); e += 256) sW4[e] = gW4[e];
  const float* gnf = nbr_fea + (size_t)a0 * M_NBR * NBR_FEA;
  for (int e = tid; e < EDGES * NBR_FEA; e += 256) {
    int r = e / NBR_FEA;
    int k = e - r * NBR_FEA;
    snf[r * NF_STRIDE + k] = (_Float16)gnf[e];
  }
  for (int e = tid; e < EDGES; e += 256) {
    snf[e * NF_STRIDE + 41] = (_Float16)0.f;
    snf[e * NF_STRIDE + 42] = (_Float16)0.f;
    snf[e * NF_STRIDE + 43] = (_Float16)0.f;
    sidx[e] = nidx[(size_t)a0 * M_NBR + e];
  }
}

__global__ __launch_bounds__(256, 2) void k_zstats_fb(
    const float* __restrict__ nbr_fea, const int* __restrict__ nidx,
    const float* __restrict__ y_self, const float* __restrict__ y_nbr,
    const float* __restrict__ Wf, const float* __restrict__ bf,
    float* __restrict__ gsum, float* __restrict__ gsumsq) {
  __shared__ __align__(16) _Float16 snf[EDGES * NF_STRIDE];
  __shared__ __align__(16) float sW[NBR_FEA * OUT2];
  __shared__ int sidx[EDGES];
  __shared__ float lsum[OUT2], lsumsq[OUT2];
  int tid = threadIdx.x;
  int cg = tid & 15, eg = tid >> 4;
  int c0 = cg * 4;
  if (tid < OUT2) { lsum[tid] = 0.f; lsumsq[tid] = 0.f; }
  int a0 = blockIdx.x * ZCH;
  stage_edge(nbr_fea, nidx, Wf + 2 * AF * OUT2, a0, tid, snf, sW, sidx);
  __syncthreads();
  float4 bz0 = *(const float4*)(bf + c0);
  float4 bz1 = *(const float4*)(bf + AF + c0);
  float4 sm0 = zero4(), sq0 = zero4(), sm1 = zero4(), sq1 = zero4();
  for (int c = 0; c < 2; ++c) {
    int ebase = c * 96 + eg * 6;
    int atomL = c * 8 + (eg >> 1);
    const float* ys = y_self + (size_t)(a0 + atomL) * OUT2;
    float4 y0 = *(const float4*)(ys + c0);
    float4 y1 = *(const float4*)(ys + AF + c0);
    float4 acc0[6], acc1[6];
    edge_gemm(snf, sW, ebase, c0, acc0, acc1);
#pragma unroll
    for (int e = 0; e < 6; ++e) {
      int j = sidx[ebase + e];
      const float* yn = y_nbr + (size_t)j * OUT2;
      float4 n0 = *(const float4*)(yn + c0);
      float4 n1 = *(const float4*)(yn + AF + c0);
      float4 z0, z1;
      z0.x = acc0[e].x + y0.x + n0.x + bz0.x; z0.y = acc0[e].y + y0.y + n0.y + bz0.y;
      z0.z = acc0[e].z + y0.z + n0.z + bz0.z; z0.w = acc0[e].w + y0.w + n0.w + bz0.w;
      z1.x = acc1[e].x + y1.x + n1.x + bz1.x; z1.y = acc1[e].y + y1.y + n1.y + bz1.y;
      z1.z = acc1[e].z + y1.z + n1.z + bz1.z; z1.w = acc1[e].w + y1.w + n1.w + bz1.w;
      sm0.x += z0.x; sm0.y += z0.y; sm0.z += z0.z; sm0.w += z0.w;
      sm1.x += z1.x; sm1.y += z1.y; sm1.z += z1.z; sm1.w += z1.w;
      sq0.x = fmaf(z0.x, z0.x, sq0.x); sq0.y = fmaf(z0.y, z0.y, sq0.y);
      sq0.z = fmaf(z0.z, z0.z, sq0.z); sq0.w = fmaf(z0.w, z0.w, sq0.w);
      sq1.x = fmaf(z1.x, z1.x, sq1.x); sq1.y = fmaf(z1.y, z1.y, sq1.y);
      sq1.z = fmaf(z1.z, z1.z, sq1.z); sq1.w = fmaf(z1.w, z1.w, sq1.w);
    }
  }
  atomicAdd(&lsum[c0 + 0], sm0.x); atomicAdd(&lsum[c0 + 1], sm0.y);
  atomicAdd(&lsum[c0 + 2], sm0.z); atomicAdd(&lsum[c0 + 3], sm0.w);
  atomicAdd(&lsum[AF + c0 + 0], sm1.x); atomicAdd(&lsum[AF + c0 + 1], sm1.y);
  atomicAdd(&lsum[AF + c0 + 2], sm1.z); atomicAdd(&lsum[AF + c0 + 3], sm1.w);
  atomicAdd(&lsumsq[c0 + 0], sq0.x); atomicAdd(&lsumsq[c0 + 1], sq0.y);
  atomicAdd(&lsumsq[c0 + 2], sq0.z); atomicAdd(&lsumsq[c0 + 3], sq0.w);
  atomicAdd(&lsumsq[AF + c0 + 0], sq1.x); atomicAdd(&lsumsq[AF + c0 + 1], sq1.y);
  atomicAdd(&lsumsq[AF + c0 + 2], sq1.z); atomicAdd(&lsumsq[AF + c0 + 3], sq1.w);
  __syncthreads();
  if (tid < OUT2) {
    atomicAdd(&gsum[tid], lsum[tid]);
    atomicAdd(&gsumsq[tid], lsumsq[tid]);
  }
}

// Pass 2 FAST PATH: pure stream over persisted z16.
__global__ __launch_bounds__(256, 4) void k_apply_stream(
    const __half* __restrict__ z16,
    const float* __restrict__ sc1, const float* __restrict__ sh1,
    float* __restrict__ s_out, float* __restrict__ gsum, float* __restrict__ gsumsq) {
  __shared__ float lsum[AF], lsumsq[AF];
  int tid = threadIdx.x;
  if (tid < AF) { lsum[tid] = 0.f; lsumsq[tid] = 0.f; }
  __syncthreads();
  int cg = tid & 15, a = tid >> 4;     // 16 atoms per block
  int c0 = cg * 4;
  size_t atom = (size_t)blockIdx.x * 16 + a;
  float4 f0 = *(const float4*)(sc1 + c0);
  float4 g0 = *(const float4*)(sh1 + c0);
  float4 f1 = *(const float4*)(sc1 + AF + c0);
  float4 g1 = *(const float4*)(sh1 + AF + c0);
  const __half* zr = z16 + atom * (M_NBR * OUT2);
  float4 sacc = zero4();
#pragma unroll 4
  for (int m = 0; m < M_NBR; ++m) {
    float4 zf = load_h4(zr + m * OUT2 + c0);
    float4 zc = load_h4(zr + m * OUT2 + AF + c0);
    zf.x = fmaf(zf.x, f0.x, g0.x); zf.y = fmaf(zf.y, f0.y, g0.y);
    zf.z = fmaf(zf.z, f0.z, g0.z); zf.w = fmaf(zf.w, f0.w, g0.w);
    zc.x = fmaf(zc.x, f1.x, g1.x); zc.y = fmaf(zc.y, f1.y, g1.y);
    zc.z = fmaf(zc.z, f1.z, g1.z); zc.w = fmaf(zc.w, f1.w, g1.w);
    sacc.x = fmaf(sigmoid_f(zf.x), softplus_f(zc.x), sacc.x);
    sacc.y = fmaf(sigmoid_f(zf.y), softplus_f(zc.y), sacc.y);
    sacc.z = fmaf(sigmoid_f(zf.z), softplus_f(zc.z), sacc.z);
    sacc.w = fmaf(sigmoid_f(zf.w), softplus_f(zc.w), sacc.w);
  }
  *(float4*)(s_out + atom * AF + c0) = sacc;
  float4 sq;
  sq.x = sacc.x * sacc.x; sq.y = sacc.y * sacc.y;
  sq.z = sacc.z * sacc.z; sq.w = sacc.w * sacc.w;
  sacc.x += __shfl_xor(sacc.x, 16, 64); sacc.y += __shfl_xor(sacc.y, 16, 64);
  sacc.z += __shfl_xor(sacc.z, 16, 64); sacc.w += __shfl_xor(sacc.w, 16, 64);
  sq.x += __shfl_xor(sq.x, 16, 64); sq.y += __shfl_xor(sq.y, 16, 64);
  sq.z += __shfl_xor(sq.z, 16, 64); sq.w += __shfl_xor(sq.w, 16, 64);
  sacc.x += __shfl_xor(sacc.x, 32, 64); sacc.y += __shfl_xor(sacc.y, 32, 64);
  sacc.z += __shfl_xor(sacc.z, 32, 64); sacc.w += __shfl_xor(sacc.w, 32, 64);
  sq.x += __shfl_xor(sq.x, 32, 64); sq.y += __shfl_xor(sq.y, 32, 64);
  sq.z += __shfl_xor(sq.z, 32, 64); sq.w += __shfl_xor(sq.w, 32, 64);
  if ((tid & 48) == 0) {
    atomicAdd(&lsum[c0 + 0], sacc.x); atomicAdd(&lsum[c0 + 1], sacc.y);
    atomicAdd(&lsum[c0 + 2], sacc.z); atomicAdd(&lsum[c0 + 3], sacc.w);
    atomicAdd(&lsumsq[c0 + 0], sq.x); atomicAdd(&lsumsq[c0 + 1], sq.y);
    atomicAdd(&lsumsq[c0 + 2], sq.z); atomicAdd(&lsumsq[c0 + 3], sq.w);
  }
  __syncthreads();
  if (tid < AF) {
    atomicAdd(&gsum[tid], lsum[tid]);
    atomicAdd(&gsumsq[tid], lsumsq[tid]);
  }
}

// Pass 2 FALLBACK (ws too small): recompute z.
__global__ __launch_bounds__(256, 2) void k_apply(
    const float* __restrict__ nbr_fea, const int* __restrict__ nidx,
    const float* __restrict__ y_self, const float* __restrict__ y_nbr,
    const float* __restrict__ Wf, const float* __restrict__ bf,
    const float* __restrict__ sc1, const float* __restrict__ sh1,
    float* __restrict__ s_out, float* __restrict__ gsum, float* __restrict__ gsumsq) {
  __shared__ __align__(16) _Float16 snf[EDGES * NF_STRIDE];
  __shared__ __align__(16) float sW[NBR_FEA * OUT2];
  __shared__ int sidx[EDGES];
  __shared__ float lsum[AF], lsumsq[AF];
  int tid = threadIdx.x;
  int cg = tid & 15, eg = tid >> 4;
  int c0 = cg * 4;
  if (tid < AF) { lsum[tid] = 0.f; lsumsq[tid] = 0.f; }
  int a0 = blockIdx.x * ZCH;
  stage_edge(nbr_fea, nidx, Wf + 2 * AF * OUT2, a0, tid, snf, sW, sidx);
  __syncthreads();
  float4 bz0 = *(const float4*)(bf + c0);
  float4 bz1 = *(const float4*)(bf + AF + c0);
  float4 f0 = *(const float4*)(sc1 + c0);
  float4 g0 = *(const float4*)(sh1 + c0);
  float4 f1 = *(const float4*)(sc1 + AF + c0);
  float4 g1 = *(const float4*)(sh1 + AF + c0);
  for (int c = 0; c < 2; ++c) {
    int ebase = c * 96 + eg * 6;
    int atomL = c * 8 + (eg >> 1);
    const float* ys = y_self + (size_t)(a0 + atomL) * OUT2;
    float4 y0 = *(const float4*)(ys + c0);
    float4 y1 = *(const float4*)(ys + AF + c0);
    float4 acc0[6], acc1[6];
    edge_gemm(snf, sW, ebase, c0, acc0, acc1);
    float4 sacc = zero4();
#pragma unroll
    for (int e = 0; e < 6; ++e) {
      int j = sidx[ebase + e];
      const float* yn = y_nbr + (size_t)j * OUT2;
      float4 n0 = *(const float4*)(yn + c0);
      float4 n1 = *(const float4*)(yn + AF + c0);
      float4 z0, z1;
      z0.x = fmaf(acc0[e].x + y0.x + n0.x + bz0.x, f0.x, g0.x);
      z0.y = fmaf(acc0[e].y + y0.y + n0.y + bz0.y, f0.y, g0.y);
      z0.z = fmaf(acc0[e].z + y0.z + n0.z + bz0.z, f0.z, g0.z);
      z0.w = fmaf(acc0[e].w + y0.w + n0.w + bz0.w, f0.w, g0.w);
      z1.x = fmaf(acc1[e].x + y1.x + n1.x + bz1.x, f1.x, g1.x);
      z1.y = fmaf(acc1[e].y + y1.y + n1.y + bz1.y, f1.y, g1.y);
      z1.z = fmaf(acc1[e].z + y1.z + n1.z + bz1.z, f1.z, g1.z);
      z1.w = fmaf(acc1[e].w + y1.w + n1.w + bz1.w, f1.w, g1.w);
      sacc.x = fmaf(sigmoid_f(z0.x), softplus_f(z1.x), sacc.x);
      sacc.y = fmaf(sigmoid_f(z0.y), softplus_f(z1.y), sacc.y);
      sacc.z = fmaf(sigmoid_f(z0.z), softplus_f(z1.z), sacc.z);
      sacc.w = fmaf(sigmoid_f(z0.w), softplus_f(z1.w), sacc.w);
    }
    sacc.x += __shfl_xor(sacc.x, 16, 64);
    sacc.y += __shfl_xor(sacc.y, 16, 64);
    sacc.z += __shfl_xor(sacc.z, 16, 64);
    sacc.w += __shfl_xor(sacc.w, 16, 64);
    if ((eg & 1) == 0) {
      *(float4*)(s_out + (size_t)(a0 + atomL) * AF + c0) = sacc;
      atomicAdd(&lsum[c0 + 0], sacc.x); atomicAdd(&lsum[c0 + 1], sacc.y);
      atomicAdd(&lsum[c0 + 2], sacc.z); atomicAdd(&lsum[c0 + 3], sacc.w);
      atomicAdd(&lsumsq[c0 + 0], sacc.x * sacc.x);
      atomicAdd(&lsumsq[c0 + 1], sacc.y * sacc.y);
      atomicAdd(&lsumsq[c0 + 2], sacc.z * sacc.z);
      atomicAdd(&lsumsq[c0 + 3], sacc.w * sacc.w);
    }
  }
  __syncthreads();
  if (tid < AF) {
    atomicAdd(&gsum[tid], lsum[tid]);
    atomicAdd(&gsumsq[tid], lsumsq[tid]);
  }
}

__global__ void k_finalize(const float* __restrict__ gsum, const float* __restrict__ gsumsq,
                           const float* __restrict__ gamma, const float* __restrict__ beta,
                           float* __restrict__ scale, float* __restrict__ shift,
                           int chn, float invcount) {
  int c = threadIdx.x;
  if (c < chn) {
    float m = gsum[c] * invcount;
    float v = gsumsq[c] * invcount - m * m;
    float sc = gamma[c] * rsqrtf(v + EPS);
    scale[c] = sc;
    shift[c] = beta[c] - m * sc;
  }
}

__global__ __launch_bounds__(256) void k_update(
    float* __restrict__ x, const float* __restrict__ s,
    const float* __restrict__ sc2, const float* __restrict__ sh2) {
  int e = blockIdx.x * 256 + threadIdx.x;
  if (e < N_ATOMS * AF) {
    int c = e & (AF - 1);
    float v = x[e] + s[e] * sc2[c] + sh2[c];
    x[e] = softplus_f(v);
  }
}

__global__ __launch_bounds__(128) void k_pool(
    const float* __restrict__ x, const int* __restrict__ cidx,
    const float* __restrict__ Wp, const float* __restrict__ bp,
    float* __restrict__ out) {
  __shared__ float part[2][AF];
  __shared__ float mean[AF];
  int g = blockIdx.x, tid = threadIdx.x;
  int c = tid & 63, h = tid >> 6;
  float acc = 0.f;
  for (int a = h; a < ATOMS_PER; a += 2) {
    int idx = cidx[g * ATOMS_PER + a];
    acc += x[(size_t)idx * AF + c];
  }
  part[h][c] = acc;
  __syncthreads();
  if (tid < AF) mean[tid] = (part[0][tid] + part[1][tid]) * (1.0f / ATOMS_PER);
  __syncthreads();
  float o = bp[tid];
#pragma unroll
  for (int k = 0; k < AF; ++k) o += mean[k] * Wp[k * OUT_DIM + tid];
  out[(size_t)g * OUT_DIM + tid] = fmaxf(o, 0.f);
}

extern "C" void kernel_launch(void* const* d_in, const int* in_sizes, int n_in,
                              void* d_out, int out_size, void* d_ws, size_t ws_size,
                              hipStream_t stream) {
  const float* atom_fea = (const float*)d_in[0];
  const float* nbr_fea  = (const float*)d_in[1];
  const int*   nbr_idx  = (const int*)d_in[2];
  const int*   cidx     = (const int*)d_in[3];
  const float* W_embed  = (const float*)d_in[4];
  const float* b_embed  = (const float*)d_in[5];
  const float* W_full   = (const float*)d_in[6];
  const float* b_full   = (const float*)d_in[7];
  const float* bn1_g    = (const float*)d_in[8];
  const float* bn1_b    = (const float*)d_in[9];
  const float* bn2_g    = (const float*)d_in[10];
  const float* bn2_b    = (const float*)d_in[11];
  const float* W_pool   = (const float*)d_in[12];
  const float* b_pool   = (const float*)d_in[13];
  float* out = (float*)d_out;

  float* ws = (float*)d_ws;
  size_t off = 0;
  float* x      = ws + off; off += (size_t)N_ATOMS * AF;
  float* y_self = ws + off; off += (size_t)N_ATOMS * OUT2;
  float* y_nbr  = ws + off; off += (size_t)N_ATOMS * OUT2;
  float* s_buf  = ws + off; off += (size_t)N_ATOMS * AF;
  float* sums   = ws + off; off += (size_t)N_CONV * 384;   // sum1/sumsq1/sum2/sumsq2
  float* affine = ws + off; off += (size_t)N_CONV * 384;   // sc1/sh1/sc2/sh2

  size_t base_bytes = (off * sizeof(float) + 255) & ~(size_t)255;  // 256B align z16
  size_t z_bytes = (size_t)N_ATOMS * M_NBR * OUT2 * sizeof(__half);   // 307.2 MB
  bool fast = ws_size >= base_bytes + z_bytes;
  __half* z16 = fast ? (__half*)((char*)d_ws + base_bytes) : nullptr;

  hipMemsetAsync(sums, 0, (size_t)N_CONV * 384 * sizeof(float), stream);

  k_embed<<<(N_ATOMS + 63) / 64, 256, 0, stream>>>(atom_fea, W_embed, b_embed, x);

  for (int i = 0; i < N_CONV; ++i) {
    const float* Wf = W_full + (size_t)i * IN_FULL * OUT2;
    const float* bf = b_full + (size_t)i * OUT2;
    float* sum1   = sums + (size_t)i * 384;
    float* sumsq1 = sum1 + OUT2;
    float* sum2   = sumsq1 + OUT2;
    float* sumsq2 = sum2 + AF;
    float* sc1 = affine + (size_t)i * 384;
    float* sh1 = sc1 + OUT2;
    float* sc2 = sh1 + OUT2;
    float* sh2 = sc2 + AF;

    k_ysn<<<N_ATOMS / YB_ATOMS, 256, 0, stream>>>(x, Wf, y_self, y_nbr);
    if (fast) {
      k_zstats_p<1><<<ZP_BLOCKS, 256, 0, stream>>>(
          nbr_fea, nbr_idx, y_self, y_nbr, Wf, bf, sum1, sumsq1, z16);
    } else {
      k_zstats_fb<<<N_ATOMS / ZCH, 256, 0, stream>>>(
          nbr_fea, nbr_idx, y_self, y_nbr, Wf, bf, sum1, sumsq1);
    }
    k_finalize<<<1, 128, 0, stream>>>(sum1, sumsq1, bn1_g + i * OUT2, bn1_b + i * OUT2,
                                      sc1, sh1, OUT2, 1.0f / ((float)N_ATOMS * M_NBR));
    if (fast) {
      k_apply_stream<<<N_ATOMS / 16, 256, 0, stream>>>(z16, sc1, sh1, s_buf,
                                                       sum2, sumsq2);
    } else {
      k_apply<<<N_ATOMS / ZCH, 256, 0, stream>>>(nbr_fea, nbr_idx, y_self, y_nbr,
                                                 Wf, bf, sc1, sh1, s_buf, sum2, sumsq2);
    }
    k_finalize<<<1, 128, 0, stream>>>(sum2, sumsq2, bn2_g + i * AF, bn2_b + i * AF,
                                      sc2, sh2, AF, 1.0f / (float)N_ATOMS);
    k_update<<<(N_ATOMS * AF + 255) / 256, 256, 0, stream>>>(x, s_buf, sc2, sh2);
  }

  k_pool<<<N_CRYSTALS, 128, 0, stream>>>(x, cidx, W_pool, b_pool, out);
}

// Round 9
// 1871.896 us; speedup vs baseline: 1.3208x; 1.0510x over previous
//
#include <hip/hip_runtime.h>
#include <hip/hip_fp16.h>
#include <math.h>

#define N_ATOMS 100000
#define M_NBR 12
#define ORIG_FEA 92
#define NBR_FEA 41
#define AF 64
#define OUT2 128          // 2*AF
#define IN_FULL 169       // 2*AF + NBR_FEA
#define N_CONV 3
#define OUT_DIM 128
#define N_CRYSTALS 2000
#define ATOMS_PER 50
#define EPS 1e-5f

#define ZCH 16            // atoms per chunk (100000 % 16 == 0)
#define EDGES (ZCH * M_NBR)          // 192
#define NF_STRIDE 44      // padded fp16 row stride (8B-aligned)
#define YB_ATOMS 80       // atoms per ysn block (100000 % 80 == 0)
#define YB_CHUNK 16
#define ZP_BLOCKS 1024    // persistent zstats grid
#define NCHUNKS (N_ATOMS / ZCH)      // 6250

typedef _Float16 h4 __attribute__((ext_vector_type(4)));

// cheap softplus: log1p(t)->log(1+t) adds only ~2^-24 abs error (result feeds sums)
__device__ __forceinline__ float softplus_f(float x) {
    return fmaxf(x, 0.0f) + __logf(1.0f + __expf(-fabsf(x)));
}
__device__ __forceinline__ float sigmoid_f(float x) {
    return __builtin_amdgcn_rcpf(1.0f + __expf(-x));   // v_rcp_f32, ~1ulp
}
__device__ __forceinline__ void fma4(float4& a, float s, const float4& b) {
    a.x = fmaf(s, b.x, a.x); a.y = fmaf(s, b.y, a.y);
    a.z = fmaf(s, b.z, a.z); a.w = fmaf(s, b.w, a.w);
}
__device__ __forceinline__ float4 zero4() { return make_float4(0.f, 0.f, 0.f, 0.f); }

union H4 { uint2 u; __half2 h[2]; };
__device__ __forceinline__ void store_h4(__half* p, float4 v) {
    H4 t;
    t.h[0] = __floats2half2_rn(v.x, v.y);
    t.h[1] = __floats2half2_rn(v.z, v.w);
    *(uint2*)p = t.u;
}
__device__ __forceinline__ float4 load_h4(const __half* p) {
    H4 t; t.u = *(const uint2*)p;
    float2 a = __half22float2(t.h[0]);
    float2 b = __half22float2(t.h[1]);
    return make_float4(a.x, a.y, b.x, b.y);
}

// x[n][c] = b[c] + sum_k af[n][k]*W[k][c]   (c<64, k<92)
__global__ __launch_bounds__(256, 2) void k_embed(
    const float* __restrict__ af, const float* __restrict__ W,
    const float* __restrict__ b, float* __restrict__ x) {
  __shared__ __align__(16) float saf[64 * ORIG_FEA];
  int a0 = blockIdx.x * 64;
  int na = min(64, N_ATOMS - a0);
  int tid = threadIdx.x;
  int c = tid & 63, rgrp = tid >> 6;
  float w[ORIG_FEA];
#pragma unroll
  for (int k = 0; k < ORIG_FEA; ++k) w[k] = W[k * AF + c];
  int n4 = na * (ORIG_FEA / 4);
  const float4* g4 = (const float4*)(af + (size_t)a0 * ORIG_FEA);
  float4* s4 = (float4*)saf;
  for (int e = tid; e < n4; e += 256) s4[e] = g4[e];
  __syncthreads();
  float bc = b[c];
  for (int a = rgrp; a < na; a += 4) {
    float acc = bc;
    const float4* row = (const float4*)(saf + a * ORIG_FEA);
#pragma unroll
    for (int q = 0; q < ORIG_FEA / 4; ++q) {
      float4 v = row[q];
      acc = fmaf(v.x, w[4 * q], acc);
      acc = fmaf(v.y, w[4 * q + 1], acc);
      acc = fmaf(v.z, w[4 * q + 2], acc);
      acc = fmaf(v.w, w[4 * q + 3], acc);
    }
    x[(size_t)(a0 + a) * AF + c] = acc;
  }
}

// y GEMM: [100k x 64] @ [64 x 256] -> y_self[n][128], y_nbr[n][128].
__global__ __launch_bounds__(256, 2) void k_ysn(
    const float* __restrict__ x, const float* __restrict__ Wf,
    float* __restrict__ y_self, float* __restrict__ y_nbr) {
  __shared__ __align__(16) float sW2[64 * 256];
  __shared__ __align__(16) float sx[YB_CHUNK * AF];
  int tid = threadIdx.x;
  int cg = tid & 31, ag = tid >> 5;     // cg: ch-quad, ag: atom-pair
  int c0 = cg * 4;
  {  // stage W': cols 0..127 = Wf[0:64][:], cols 128..255 = Wf[64:128][:]
    float4* s4 = (float4*)sW2;
    const float4* g4 = (const float4*)Wf;
    for (int e = tid; e < 64 * 64; e += 256) {
      int r = e >> 6, q = e & 63;
      s4[r * 64 + q] = (q < 32) ? g4[r * 32 + q] : g4[(64 + r) * 32 + (q - 32)];
    }
  }
  int ab = blockIdx.x * YB_ATOMS;
  for (int cc = 0; cc < YB_ATOMS / YB_CHUNK; ++cc) {
    int a0 = ab + cc * YB_CHUNK;
    __syncthreads();
    {
      float4* s4 = (float4*)sx;
      const float4* g4 = (const float4*)(x + (size_t)a0 * AF);
      for (int e = tid; e < YB_CHUNK * AF / 4; e += 256) s4[e] = g4[e];
    }
    __syncthreads();
    float4 accs[2] = {zero4(), zero4()};
    float4 accn[2] = {zero4(), zero4()};
    for (int k0 = 0; k0 < AF; k0 += 4) {
      float4 av0 = *(const float4*)(sx + (ag * 2 + 0) * AF + k0);
      float4 av1 = *(const float4*)(sx + (ag * 2 + 1) * AF + k0);
#pragma unroll
      for (int kk = 0; kk < 4; ++kk) {
        float4 b0 = *(const float4*)(sW2 + (k0 + kk) * 256 + c0);
        float4 b1 = *(const float4*)(sW2 + (k0 + kk) * 256 + 128 + c0);
        float s0 = (kk == 0) ? av0.x : (kk == 1) ? av0.y : (kk == 2) ? av0.z : av0.w;
        float s1 = (kk == 0) ? av1.x : (kk == 1) ? av1.y : (kk == 2) ? av1.z : av1.w;
        fma4(accs[0], s0, b0); fma4(accn[0], s0, b1);
        fma4(accs[1], s1, b0); fma4(accn[1], s1, b1);
      }
    }
#pragma unroll
    for (int t = 0; t < 2; ++t) {
      size_t n = (size_t)(a0 + ag * 2 + t);
      *(float4*)(y_self + n * OUT2 + c0) = accs[t];
      *(float4*)(y_nbr + n * OUT2 + c0) = accn[t];
    }
  }
}

// Edge GEMM micro-kernel: A fp16 from LDS (cvt at use), B f32 from LDS, f32 FMA.
// Each LDS read of b0/b1 is reused by 6 edges (key LDS-BW amortization).
__device__ __forceinline__ void edge_gemm(
    const _Float16* snf, const float* sW, int ebase, int c0,
    float4 acc0[6], float4 acc1[6]) {
#pragma unroll
  for (int e = 0; e < 6; ++e) { acc0[e] = zero4(); acc1[e] = zero4(); }
  for (int k0 = 0; k0 < 40; k0 += 4) {
    h4 av[6];
#pragma unroll
    for (int e = 0; e < 6; ++e)
      av[e] = *(const h4*)(snf + (ebase + e) * NF_STRIDE + k0);
#pragma unroll
    for (int kk = 0; kk < 4; ++kk) {
      float4 b0 = *(const float4*)(sW + (k0 + kk) * OUT2 + c0);
      float4 b1 = *(const float4*)(sW + (k0 + kk) * OUT2 + AF + c0);
#pragma unroll
      for (int e = 0; e < 6; ++e) {
        float s = (float)av[e][kk];
        fma4(acc0[e], s, b0);
        fma4(acc1[e], s, b1);
      }
    }
  }
  {  // k = 40 tail
    float4 b0 = *(const float4*)(sW + 40 * OUT2 + c0);
    float4 b1 = *(const float4*)(sW + 40 * OUT2 + AF + c0);
#pragma unroll
    for (int e = 0; e < 6; ++e) {
      float s = (float)snf[(ebase + e) * NF_STRIDE + 40];
      fma4(acc0[e], s, b0);
      fma4(acc1[e], s, b1);
    }
  }
}

// ---------------- FAST PATH pass 1: PERSISTENT blocks + double-buffered snf ----------
// Empirical occupancy law (r1/r4/r5/r8): VGPR<=64 -> ~45%; VGPR in (64,128] -> ~22%
// (2 blocks/CU) regardless of LDS in 38-57KB. The 48-float acc tile pins us >64 VGPR,
// so LDS up to ~64KB is FREE -> spend it on a second snf buffer. Loop becomes
// stage(next) || compute(cur) with ONE barrier per chunk (was 2), hiding the staging
// global-load latency under ~3900 FMAs of edge_gemm.
template <int WZ>
__global__ __launch_bounds__(256, 2) void k_zstats_p(
    const float* __restrict__ nbr_fea, const int* __restrict__ nidx,
    const float* __restrict__ y_self, const float* __restrict__ y_nbr,
    const float* __restrict__ Wf, const float* __restrict__ bf,
    float* __restrict__ gsum, float* __restrict__ gsumsq,
    __half* __restrict__ z16) {
  __shared__ __align__(16) _Float16 snf[2 * EDGES * NF_STRIDE];  // 2 x 16896 B
  __shared__ __align__(16) float sW[NBR_FEA * OUT2];             // 21504 B
  __shared__ __align__(16) unsigned char sbuf[1536];             // sidx[2] / reduce alias
  int tid = threadIdx.x;
  int cg = tid & 15, eg = tid >> 4;
  int c0 = cg * 4;
  {  // stage W once per (persistent) block
    float4* sW4 = (float4*)sW;
    const float4* gW4 = (const float4*)(Wf + 2 * AF * OUT2);
    for (int e = tid; e < NBR_FEA * (OUT2 / 4); e += 256) sW4[e] = gW4[e];
  }
  // prologue: stage chunk 0 into buffer 0
  {
    int a0 = blockIdx.x * ZCH;
    const float* gnf = nbr_fea + (size_t)a0 * M_NBR * NBR_FEA;
    _Float16* s = snf;
    int* si = (int*)sbuf;
    for (int e = tid; e < EDGES * NBR_FEA; e += 256) {
      int r = e / NBR_FEA;
      int k = e - r * NBR_FEA;
      s[r * NF_STRIDE + k] = (_Float16)gnf[e];
    }
    for (int e = tid; e < EDGES; e += 256) {
      s[e * NF_STRIDE + 41] = (_Float16)0.f;
      s[e * NF_STRIDE + 42] = (_Float16)0.f;
      s[e * NF_STRIDE + 43] = (_Float16)0.f;
      si[e] = nidx[(size_t)a0 * M_NBR + e];
    }
  }
  __syncthreads();
  float4 bz0 = *(const float4*)(bf + c0);
  float4 bz1 = *(const float4*)(bf + AF + c0);
  float4 sm0 = zero4(), sq0 = zero4(), sm1 = zero4(), sq1 = zero4();
  int buf = 0;
  for (int cc = blockIdx.x; cc < NCHUNKS; cc += ZP_BLOCKS) {
    // ---- issue next chunk's stage into the other buffer (overlaps compute) ----
    int ccn = cc + ZP_BLOCKS;
    if (ccn < NCHUNKS) {
      int an = ccn * ZCH;
      const float* gnf = nbr_fea + (size_t)an * M_NBR * NBR_FEA;
      _Float16* s = snf + (buf ^ 1) * (EDGES * NF_STRIDE);
      int* si = (int*)sbuf + (buf ^ 1) * EDGES;
      for (int e = tid; e < EDGES * NBR_FEA; e += 256) {
        int r = e / NBR_FEA;
        int k = e - r * NBR_FEA;
        s[r * NF_STRIDE + k] = (_Float16)gnf[e];
      }
      for (int e = tid; e < EDGES; e += 256) {
        s[e * NF_STRIDE + 41] = (_Float16)0.f;
        s[e * NF_STRIDE + 42] = (_Float16)0.f;
        s[e * NF_STRIDE + 43] = (_Float16)0.f;
        si[e] = nidx[(size_t)an * M_NBR + e];
      }
    }
    // ---- compute current chunk ----
    int a0 = cc * ZCH;
    const _Float16* scur = snf + buf * (EDGES * NF_STRIDE);
    const int* sicur = (const int*)sbuf + buf * EDGES;
    for (int c = 0; c < 2; ++c) {
      int ebase = c * 96 + eg * 6;
      int atomL = c * 8 + (eg >> 1);
      const float* ys = y_self + (size_t)(a0 + atomL) * OUT2;
      float4 y0 = *(const float4*)(ys + c0);
      float4 y1 = *(const float4*)(ys + AF + c0);
      float4 acc0[6], acc1[6];
      edge_gemm(scur, sW, ebase, c0, acc0, acc1);
#pragma unroll
      for (int e = 0; e < 6; ++e) {
        int j = sicur[ebase + e];
        const float* yn = y_nbr + (size_t)j * OUT2;
        float4 n0 = *(const float4*)(yn + c0);
        float4 n1 = *(const float4*)(yn + AF + c0);
        float4 z0, z1;
        z0.x = acc0[e].x + y0.x + n0.x + bz0.x; z0.y = acc0[e].y + y0.y + n0.y + bz0.y;
        z0.z = acc0[e].z + y0.z + n0.z + bz0.z; z0.w = acc0[e].w + y0.w + n0.w + bz0.w;
        z1.x = acc1[e].x + y1.x + n1.x + bz1.x; z1.y = acc1[e].y + y1.y + n1.y + bz1.y;
        z1.z = acc1[e].z + y1.z + n1.z + bz1.z; z1.w = acc1[e].w + y1.w + n1.w + bz1.w;
        if (WZ) {
          __half* zp = z16 + ((size_t)a0 * M_NBR + ebase + e) * OUT2 + c0;
          store_h4(zp, z0);
          store_h4(zp + AF, z1);
        }
        sm0.x += z0.x; sm0.y += z0.y; sm0.z += z0.z; sm0.w += z0.w;
        sm1.x += z1.x; sm1.y += z1.y; sm1.z += z1.z; sm1.w += z1.w;
        sq0.x = fmaf(z0.x, z0.x, sq0.x); sq0.y = fmaf(z0.y, z0.y, sq0.y);
        sq0.z = fmaf(z0.z, z0.z, sq0.z); sq0.w = fmaf(z0.w, z0.w, sq0.w);
        sq1.x = fmaf(z1.x, z1.x, sq1.x); sq1.y = fmaf(z1.y, z1.y, sq1.y);
        sq1.z = fmaf(z1.z, z1.z, sq1.z); sq1.w = fmaf(z1.w, z1.w, sq1.w);
      }
    }
    __syncthreads();   // stage(next) complete; compute(cur) done -> buffers may swap
    buf ^= 1;
  }
  // ---- once-per-block reduce (sidx no longer needed; reuse sbuf) ----
  float* lsum = (float*)sbuf;          // [OUT2]
  float* lsumsq = lsum + OUT2;         // [OUT2]
  ((float*)sbuf)[tid] = 0.f;           // 256 threads zero 1024 B
  __syncthreads();
  atomicAdd(&lsum[c0 + 0], sm0.x); atomicAdd(&lsum[c0 + 1], sm0.y);
  atomicAdd(&lsum[c0 + 2], sm0.z); atomicAdd(&lsum[c0 + 3], sm0.w);
  atomicAdd(&lsum[AF + c0 + 0], sm1.x); atomicAdd(&lsum[AF + c0 + 1], sm1.y);
  atomicAdd(&lsum[AF + c0 + 2], sm1.z); atomicAdd(&lsum[AF + c0 + 3], sm1.w);
  atomicAdd(&lsumsq[c0 + 0], sq0.x); atomicAdd(&lsumsq[c0 + 1], sq0.y);
  atomicAdd(&lsumsq[c0 + 2], sq0.z); atomicAdd(&lsumsq[c0 + 3], sq0.w);
  atomicAdd(&lsumsq[AF + c0 + 0], sq1.x); atomicAdd(&lsumsq[AF + c0 + 1], sq1.y);
  atomicAdd(&lsumsq[AF + c0 + 2], sq1.z); atomicAdd(&lsumsq[AF + c0 + 3], sq1.w);
  __syncthreads();
  if (tid < OUT2) {
    atomicAdd(&gsum[tid], lsum[tid]);
    atomicAdd(&gsumsq[tid], lsumsq[tid]);
  }
}

// ---------------- fallback-path machinery (ws too small) ----------------
__device__ __forceinline__ void stage_edge(
    const float* __restrict__ nbr_fea, const int* __restrict__ nidx,
    const float* __restrict__ We, int a0, int tid,
    _Float16* snf, float* sW, int* sidx) {
  float4* sW4 = (float4*)sW;
  const float4* gW4 = (const float4*)We;
  for (int e = tid; e < NBR_FEA * (OUT2 / 4); e += 256) sW4[e] = gW4[e];
  const float* gnf = nbr_fea + (size_t)a0 * M_NBR * NBR_FEA;
  for (int e = tid; e < EDGES * NBR_FEA; e += 256) {
    int r = e / NBR_FEA;
    int k = e - r * NBR_FEA;
    snf[r * NF_STRIDE + k] = (_Float16)gnf[e];
  }
  for (int e = tid; e < EDGES; e += 256) {
    snf[e * NF_STRIDE + 41] = (_Float16)0.f;
    snf[e * NF_STRIDE + 42] = (_Float16)0.f;
    snf[e * NF_STRIDE + 43] = (_Float16)0.f;
    sidx[e] = nidx[(size_t)a0 * M_NBR + e];
  }
}

__global__ __launch_bounds__(256, 2) void k_zstats_fb(
    const float* __restrict__ nbr_fea, const int* __restrict__ nidx,
    const float* __restrict__ y_self, const float* __restrict__ y_nbr,
    const float* __restrict__ Wf, const float* __restrict__ bf,
    float* __restrict__ gsum, float* __restrict__ gsumsq) {
  __shared__ __align__(16) _Float16 snf[EDGES * NF_STRIDE];
  __shared__ __align__(16) float sW[NBR_FEA * OUT2];
  __shared__ int sidx[EDGES];
  __shared__ float lsum[OUT2], lsumsq[OUT2];
  int tid = threadIdx.x;
  int cg = tid & 15, eg = tid >> 4;
  int c0 = cg * 4;
  if (tid < OUT2) { lsum[tid] = 0.f; lsumsq[tid] = 0.f; }
  int a0 = blockIdx.x * ZCH;
  stage_edge(nbr_fea, nidx, Wf + 2 * AF * OUT2, a0, tid, snf, sW, sidx);
  __syncthreads();
  float4 bz0 = *(const float4*)(bf + c0);
  float4 bz1 = *(const float4*)(bf + AF + c0);
  float4 sm0 = zero4(), sq0 = zero4(), sm1 = zero4(), sq1 = zero4();
  for (int c = 0; c < 2; ++c) {
    int ebase = c * 96 + eg * 6;
    int atomL = c * 8 + (eg >> 1);
    const float* ys = y_self + (size_t)(a0 + atomL) * OUT2;
    float4 y0 = *(const float4*)(ys + c0);
    float4 y1 = *(const float4*)(ys + AF + c0);
    float4 acc0[6], acc1[6];
    edge_gemm(snf, sW, ebase, c0, acc0, acc1);
#pragma unroll
    for (int e = 0; e < 6; ++e) {
      int j = sidx[ebase + e];
      const float* yn = y_nbr + (size_t)j * OUT2;
      float4 n0 = *(const float4*)(yn + c0);
      float4 n1 = *(const float4*)(yn + AF + c0);
      float4 z0, z1;
      z0.x = acc0[e].x + y0.x + n0.x + bz0.x; z0.y = acc0[e].y + y0.y + n0.y + bz0.y;
      z0.z = acc0[e].z + y0.z + n0.z + bz0.z; z0.w = acc0[e].w + y0.w + n0.w + bz0.w;
      z1.x = acc1[e].x + y1.x + n1.x + bz1.x; z1.y = acc1[e].y + y1.y + n1.y + bz1.y;
      z1.z = acc1[e].z + y1.z + n1.z + bz1.z; z1.w = acc1[e].w + y1.w + n1.w + bz1.w;
      sm0.x += z0.x; sm0.y += z0.y; sm0.z += z0.z; sm0.w += z0.w;
      sm1.x += z1.x; sm1.y += z1.y; sm1.z += z1.z; sm1.w += z1.w;
      sq0.x = fmaf(z0.x, z0.x, sq0.x); sq0.y = fmaf(z0.y, z0.y, sq0.y);
      sq0.z = fmaf(z0.z, z0.z, sq0.z); sq0.w = fmaf(z0.w, z0.w, sq0.w);
      sq1.x = fmaf(z1.x, z1.x, sq1.x); sq1.y = fmaf(z1.y, z1.y, sq1.y);
      sq1.z = fmaf(z1.z, z1.z, sq1.z); sq1.w = fmaf(z1.w, z1.w, sq1.w);
    }
  }
  atomicAdd(&lsum[c0 + 0], sm0.x); atomicAdd(&lsum[c0 + 1], sm0.y);
  atomicAdd(&lsum[c0 + 2], sm0.z); atomicAdd(&lsum[c0 + 3], sm0.w);
  atomicAdd(&lsum[AF + c0 + 0], sm1.x); atomicAdd(&lsum[AF + c0 + 1], sm1.y);
  atomicAdd(&lsum[AF + c0 + 2], sm1.z); atomicAdd(&lsum[AF + c0 + 3], sm1.w);
  atomicAdd(&lsumsq[c0 + 0], sq0.x); atomicAdd(&lsumsq[c0 + 1], sq0.y);
  atomicAdd(&lsumsq[c0 + 2], sq0.z); atomicAdd(&lsumsq[c0 + 3], sq0.w);
  atomicAdd(&lsumsq[AF + c0 + 0], sq1.x); atomicAdd(&lsumsq[AF + c0 + 1], sq1.y);
  atomicAdd(&lsumsq[AF + c0 + 2], sq1.z); atomicAdd(&lsumsq[AF + c0 + 3], sq1.w);
  __syncthreads();
  if (tid < OUT2) {
    atomicAdd(&gsum[tid], lsum[tid]);
    atomicAdd(&gsumsq[tid], lsumsq[tid]);
  }
}

// Pass 2 FAST PATH: pure stream over persisted z16.
__global__ __launch_bounds__(256, 4) void k_apply_stream(
    const __half* __restrict__ z16,
    const float* __restrict__ sc1, const float* __restrict__ sh1,
    float* __restrict__ s_out, float* __restrict__ gsum, float* __restrict__ gsumsq) {
  __shared__ float lsum[AF], lsumsq[AF];
  int tid = threadIdx.x;
  if (tid < AF) { lsum[tid] = 0.f; lsumsq[tid] = 0.f; }
  __syncthreads();
  int cg = tid & 15, a = tid >> 4;     // 16 atoms per block
  int c0 = cg * 4;
  size_t atom = (size_t)blockIdx.x * 16 + a;
  float4 f0 = *(const float4*)(sc1 + c0);
  float4 g0 = *(const float4*)(sh1 + c0);
  float4 f1 = *(const float4*)(sc1 + AF + c0);
  float4 g1 = *(const float4*)(sh1 + AF + c0);
  const __half* zr = z16 + atom * (M_NBR * OUT2);
  float4 sacc = zero4();
#pragma unroll 4
  for (int m = 0; m < M_NBR; ++m) {
    float4 zf = load_h4(zr + m * OUT2 + c0);
    float4 zc = load_h4(zr + m * OUT2 + AF + c0);
    zf.x = fmaf(zf.x, f0.x, g0.x); zf.y = fmaf(zf.y, f0.y, g0.y);
    zf.z = fmaf(zf.z, f0.z, g0.z); zf.w = fmaf(zf.w, f0.w, g0.w);
    zc.x = fmaf(zc.x, f1.x, g1.x); zc.y = fmaf(zc.y, f1.y, g1.y);
    zc.z = fmaf(zc.z, f1.z, g1.z); zc.w = fmaf(zc.w, f1.w, g1.w);
    sacc.x = fmaf(sigmoid_f(zf.x), softplus_f(zc.x), sacc.x);
    sacc.y = fmaf(sigmoid_f(zf.y), softplus_f(zc.y), sacc.y);
    sacc.z = fmaf(sigmoid_f(zf.z), softplus_f(zc.z), sacc.z);
    sacc.w = fmaf(sigmoid_f(zf.w), softplus_f(zc.w), sacc.w);
  }
  *(float4*)(s_out + atom * AF + c0) = sacc;
  float4 sq;
  sq.x = sacc.x * sacc.x; sq.y = sacc.y * sacc.y;
  sq.z = sacc.z * sacc.z; sq.w = sacc.w * sacc.w;
  sacc.x += __shfl_xor(sacc.x, 16, 64); sacc.y += __shfl_xor(sacc.y, 16, 64);
  sacc.z += __shfl_xor(sacc.z, 16, 64); sacc.w += __shfl_xor(sacc.w, 16, 64);
  sq.x += __shfl_xor(sq.x, 16, 64); sq.y += __shfl_xor(sq.y, 16, 64);
  sq.z += __shfl_xor(sq.z, 16, 64); sq.w += __shfl_xor(sq.w, 16, 64);
  sacc.x += __shfl_xor(sacc.x, 32, 64); sacc.y += __shfl_xor(sacc.y, 32, 64);
  sacc.z += __shfl_xor(sacc.z, 32, 64); sacc.w += __shfl_xor(sacc.w, 32, 64);
  sq.x += __shfl_xor(sq.x, 32, 64); sq.y += __shfl_xor(sq.y, 32, 64);
  sq.z += __shfl_xor(sq.z, 32, 64); sq.w += __shfl_xor(sq.w, 32, 64);
  if ((tid & 48) == 0) {
    atomicAdd(&lsum[c0 + 0], sacc.x); atomicAdd(&lsum[c0 + 1], sacc.y);
    atomicAdd(&lsum[c0 + 2], sacc.z); atomicAdd(&lsum[c0 + 3], sacc.w);
    atomicAdd(&lsumsq[c0 + 0], sq.x); atomicAdd(&lsumsq[c0 + 1], sq.y);
    atomicAdd(&lsumsq[c0 + 2], sq.z); atomicAdd(&lsumsq[c0 + 3], sq.w);
  }
  __syncthreads();
  if (tid < AF) {
    atomicAdd(&gsum[tid], lsum[tid]);
    atomicAdd(&gsumsq[tid], lsumsq[tid]);
  }
}

// Pass 2 FALLBACK (ws too small): recompute z.
__global__ __launch_bounds__(256, 2) void k_apply(
    const float* __restrict__ nbr_fea, const int* __restrict__ nidx,
    const float* __restrict__ y_self, const float* __restrict__ y_nbr,
    const float* __restrict__ Wf, const float* __restrict__ bf,
    const float* __restrict__ sc1, const float* __restrict__ sh1,
    float* __restrict__ s_out, float* __restrict__ gsum, float* __restrict__ gsumsq) {
  __shared__ __align__(16) _Float16 snf[EDGES * NF_STRIDE];
  __shared__ __align__(16) float sW[NBR_FEA * OUT2];
  __shared__ int sidx[EDGES];
  __shared__ float lsum[AF], lsumsq[AF];
  int tid = threadIdx.x;
  int cg = tid & 15, eg = tid >> 4;
  int c0 = cg * 4;
  if (tid < AF) { lsum[tid] = 0.f; lsumsq[tid] = 0.f; }
  int a0 = blockIdx.x * ZCH;
  stage_edge(nbr_fea, nidx, Wf + 2 * AF * OUT2, a0, tid, snf, sW, sidx);
  __syncthreads();
  float4 bz0 = *(const float4*)(bf + c0);
  float4 bz1 = *(const float4*)(bf + AF + c0);
  float4 f0 = *(const float4*)(sc1 + c0);
  float4 g0 = *(const float4*)(sh1 + c0);
  float4 f1 = *(const float4*)(sc1 + AF + c0);
  float4 g1 = *(const float4*)(sh1 + AF + c0);
  for (int c = 0; c < 2; ++c) {
    int ebase = c * 96 + eg * 6;
    int atomL = c * 8 + (eg >> 1);
    const float* ys = y_self + (size_t)(a0 + atomL) * OUT2;
    float4 y0 = *(const float4*)(ys + c0);
    float4 y1 = *(const float4*)(ys + AF + c0);
    float4 acc0[6], acc1[6];
    edge_gemm(snf, sW, ebase, c0, acc0, acc1);
    float4 sacc = zero4();
#pragma unroll
    for (int e = 0; e < 6; ++e) {
      int j = sidx[ebase + e];
      const float* yn = y_nbr + (size_t)j * OUT2;
      float4 n0 = *(const float4*)(yn + c0);
      float4 n1 = *(const float4*)(yn + AF + c0);
      float4 z0, z1;
      z0.x = fmaf(acc0[e].x + y0.x + n0.x + bz0.x, f0.x, g0.x);
      z0.y = fmaf(acc0[e].y + y0.y + n0.y + bz0.y, f0.y, g0.y);
      z0.z = fmaf(acc0[e].z + y0.z + n0.z + bz0.z, f0.z, g0.z);
      z0.w = fmaf(acc0[e].w + y0.w + n0.w + bz0.w, f0.w, g0.w);
      z1.x = fmaf(acc1[e].x + y1.x + n1.x + bz1.x, f1.x, g1.x);
      z1.y = fmaf(acc1[e].y + y1.y + n1.y + bz1.y, f1.y, g1.y);
      z1.z = fmaf(acc1[e].z + y1.z + n1.z + bz1.z, f1.z, g1.z);
      z1.w = fmaf(acc1[e].w + y1.w + n1.w + bz1.w, f1.w, g1.w);
      sacc.x = fmaf(sigmoid_f(z0.x), softplus_f(z1.x), sacc.x);
      sacc.y = fmaf(sigmoid_f(z0.y), softplus_f(z1.y), sacc.y);
      sacc.z = fmaf(sigmoid_f(z0.z), softplus_f(z1.z), sacc.z);
      sacc.w = fmaf(sigmoid_f(z0.w), softplus_f(z1.w), sacc.w);
    }
    sacc.x += __shfl_xor(sacc.x, 16, 64);
    sacc.y += __shfl_xor(sacc.y, 16, 64);
    sacc.z += __shfl_xor(sacc.z, 16, 64);
    sacc.w += __shfl_xor(sacc.w, 16, 64);
    if ((eg & 1) == 0) {
      *(float4*)(s_out + (size_t)(a0 + atomL) * AF + c0) = sacc;
      atomicAdd(&lsum[c0 + 0], sacc.x); atomicAdd(&lsum[c0 + 1], sacc.y);
      atomicAdd(&lsum[c0 + 2], sacc.z); atomicAdd(&lsum[c0 + 3], sacc.w);
      atomicAdd(&lsumsq[c0 + 0], sacc.x * sacc.x);
      atomicAdd(&lsumsq[c0 + 1], sacc.y * sacc.y);
      atomicAdd(&lsumsq[c0 + 2], sacc.z * sacc.z);
      atomicAdd(&lsumsq[c0 + 3], sacc.w * sacc.w);
    }
  }
  __syncthreads();
  if (tid < AF) {
    atomicAdd(&gsum[tid], lsum[tid]);
    atomicAdd(&gsumsq[tid], lsumsq[tid]);
  }
}

__global__ void k_finalize(const float* __restrict__ gsum, const float* __restrict__ gsumsq,
                           const float* __restrict__ gamma, const float* __restrict__ beta,
                           float* __restrict__ scale, float* __restrict__ shift,
                           int chn, float invcount) {
  int c = threadIdx.x;
  if (c < chn) {
    float m = gsum[c] * invcount;
    float v = gsumsq[c] * invcount - m * m;
    float sc = gamma[c] * rsqrtf(v + EPS);
    scale[c] = sc;
    shift[c] = beta[c] - m * sc;
  }
}

__global__ __launch_bounds__(256) void k_update(
    float* __restrict__ x, const float* __restrict__ s,
    const float* __restrict__ sc2, const float* __restrict__ sh2) {
  int e = blockIdx.x * 256 + threadIdx.x;
  if (e < N_ATOMS * AF) {
    int c = e & (AF - 1);
    float v = x[e] + s[e] * sc2[c] + sh2[c];
    x[e] = softplus_f(v);
  }
}

__global__ __launch_bounds__(128) void k_pool(
    const float* __restrict__ x, const int* __restrict__ cidx,
    const float* __restrict__ Wp, const float* __restrict__ bp,
    float* __restrict__ out) {
  __shared__ float part[2][AF];
  __shared__ float mean[AF];
  int g = blockIdx.x, tid = threadIdx.x;
  int c = tid & 63, h = tid >> 6;
  float acc = 0.f;
  for (int a = h; a < ATOMS_PER; a += 2) {
    int idx = cidx[g * ATOMS_PER + a];
    acc += x[(size_t)idx * AF + c];
  }
  part[h][c] = acc;
  __syncthreads();
  if (tid < AF) mean[tid] = (part[0][tid] + part[1][tid]) * (1.0f / ATOMS_PER);
  __syncthreads();
  float o = bp[tid];
#pragma unroll
  for (int k = 0; k < AF; ++k) o += mean[k] * Wp[k * OUT_DIM + tid];
  out[(size_t)g * OUT_DIM + tid] = fmaxf(o, 0.f);
}

extern "C" void kernel_launch(void* const* d_in, const int* in_sizes, int n_in,
                              void* d_out, int out_size, void* d_ws, size_t ws_size,
                              hipStream_t stream) {
  const float* atom_fea = (const float*)d_in[0];
  const float* nbr_fea  = (const float*)d_in[1];
  const int*   nbr_idx  = (const int*)d_in[2];
  const int*   cidx     = (const int*)d_in[3];
  const float* W_embed  = (const float*)d_in[4];
  const float* b_embed  = (const float*)d_in[5];
  const float* W_full   = (const float*)d_in[6];
  const float* b_full   = (const float*)d_in[7];
  const float* bn1_g    = (const float*)d_in[8];
  const float* bn1_b    = (const float*)d_in[9];
  const float* bn2_g    = (const float*)d_in[10];
  const float* bn2_b    = (const float*)d_in[11];
  const float* W_pool   = (const float*)d_in[12];
  const float* b_pool   = (const float*)d_in[13];
  float* out = (float*)d_out;

  float* ws = (float*)d_ws;
  size_t off = 0;
  float* x      = ws + off; off += (size_t)N_ATOMS * AF;
  float* y_self = ws + off; off += (size_t)N_ATOMS * OUT2;
  float* y_nbr  = ws + off; off += (size_t)N_ATOMS * OUT2;
  float* s_buf  = ws + off; off += (size_t)N_ATOMS * AF;
  float* sums   = ws + off; off += (size_t)N_CONV * 384;   // sum1/sumsq1/sum2/sumsq2
  float* affine = ws + off; off += (size_t)N_CONV * 384;   // sc1/sh1/sc2/sh2

  size_t base_bytes = (off * sizeof(float) + 255) & ~(size_t)255;  // 256B align z16
  size_t z_bytes = (size_t)N_ATOMS * M_NBR * OUT2 * sizeof(__half);   // 307.2 MB
  bool fast = ws_size >= base_bytes + z_bytes;
  __half* z16 = fast ? (__half*)((char*)d_ws + base_bytes) : nullptr;

  hipMemsetAsync(sums, 0, (size_t)N_CONV * 384 * sizeof(float), stream);

  k_embed<<<(N_ATOMS + 63) / 64, 256, 0, stream>>>(atom_fea, W_embed, b_embed, x);

  for (int i = 0; i < N_CONV; ++i) {
    const float* Wf = W_full + (size_t)i * IN_FULL * OUT2;
    const float* bf = b_full + (size_t)i * OUT2;
    float* sum1   = sums + (size_t)i * 384;
    float* sumsq1 = sum1 + OUT2;
    float* sum2   = sumsq1 + OUT2;
    float* sumsq2 = sum2 + AF;
    float* sc1 = affine + (size_t)i * 384;
    float* sh1 = sc1 + OUT2;
    float* sc2 = sh1 + OUT2;
    float* sh2 = sc2 + AF;

    k_ysn<<<N_ATOMS / YB_ATOMS, 256, 0, stream>>>(x, Wf, y_self, y_nbr);
    if (fast) {
      k_zstats_p<1><<<ZP_BLOCKS, 256, 0, stream>>>(
          nbr_fea, nbr_idx, y_self, y_nbr, Wf, bf, sum1, sumsq1, z16);
    } else {
      k_zstats_fb<<<N_ATOMS / ZCH, 256, 0, stream>>>(
          nbr_fea, nbr_idx, y_self, y_nbr, Wf, bf, sum1, sumsq1);
    }
    k_finalize<<<1, 128, 0, stream>>>(sum1, sumsq1, bn1_g + i * OUT2, bn1_b + i * OUT2,
                                      sc1, sh1, OUT2, 1.0f / ((float)N_ATOMS * M_NBR));
    if (fast) {
      k_apply_stream<<<N_ATOMS / 16, 256, 0, stream>>>(z16, sc1, sh1, s_buf,
                                                       sum2, sumsq2);
    } else {
      k_apply<<<N_ATOMS / ZCH, 256, 0, stream>>>(nbr_fea, nbr_idx, y_self, y_nbr,
                                                 Wf, bf, sc1, sh1, s_buf, sum2, sumsq2);
    }
    k_finalize<<<1, 128, 0, stream>>>(sum2, sumsq2, bn2_g + i * AF, bn2_b + i * AF,
                                      sc2, sh2, AF, 1.0f / (float)N_ATOMS);
    k_update<<<(N_ATOMS * AF + 255) / 256, 256, 0, stream>>>(x, s_buf, sc2, sh2);
  }

  k_pool<<<N_CRYSTALS, 128, 0, stream>>>(x, cidx, W_pool, b_pool, out);
}

// Round 10
// 1814.746 us; speedup vs baseline: 1.3624x; 1.0315x over previous
//
#include <hip/hip_runtime.h>
#include <hip/hip_fp16.h>
#include <math.h>

#define N_ATOMS 100000
#define M_NBR 12
#define ORIG_FEA 92
#define NBR_FEA 41
#define AF 64
#define OUT2 128          // 2*AF
#define IN_FULL 169       // 2*AF + NBR_FEA
#define N_CONV 3
#define OUT_DIM 128
#define N_CRYSTALS 2000
#define ATOMS_PER 50
#define EPS 1e-5f

#define ZCH 16            // atoms per chunk (100000 % 16 == 0)
#define EDGES (ZCH * M_NBR)          // 192
#define NF_STRIDE 44      // padded fp16 row stride (8B-aligned)
#define YB_ATOMS 80       // atoms per ysn block (100000 % 80 == 0)
#define YB_CHUNK 16
#define ZP_BLOCKS 1024    // persistent zstats grid
#define NCHUNKS (N_ATOMS / ZCH)      // 6250

typedef _Float16 h4 __attribute__((ext_vector_type(4)));

// cheap softplus: log1p(t)->log(1+t) adds only ~2^-24 abs error (result feeds sums)
__device__ __forceinline__ float softplus_f(float x) {
    return fmaxf(x, 0.0f) + __logf(1.0f + __expf(-fabsf(x)));
}
__device__ __forceinline__ float sigmoid_f(float x) {
    return __builtin_amdgcn_rcpf(1.0f + __expf(-x));   // v_rcp_f32, ~1ulp
}
__device__ __forceinline__ void fma4(float4& a, float s, const float4& b) {
    a.x = fmaf(s, b.x, a.x); a.y = fmaf(s, b.y, a.y);
    a.z = fmaf(s, b.z, a.z); a.w = fmaf(s, b.w, a.w);
}
__device__ __forceinline__ float4 zero4() { return make_float4(0.f, 0.f, 0.f, 0.f); }

union H4 { uint2 u; __half2 h[2]; };
__device__ __forceinline__ void store_h4(__half* p, float4 v) {
    H4 t;
    t.h[0] = __floats2half2_rn(v.x, v.y);
    t.h[1] = __floats2half2_rn(v.z, v.w);
    *(uint2*)p = t.u;
}
__device__ __forceinline__ float4 load_h4(const __half* p) {
    H4 t; t.u = *(const uint2*)p;
    float2 a = __half22float2(t.h[0]);
    float2 b = __half22float2(t.h[1]);
    return make_float4(a.x, a.y, b.x, b.y);
}

// x[n][c] = b[c] + sum_k af[n][k]*W[k][c]   (c<64, k<92)
__global__ __launch_bounds__(256, 2) void k_embed(
    const float* __restrict__ af, const float* __restrict__ W,
    const float* __restrict__ b, float* __restrict__ x) {
  __shared__ __align__(16) float saf[64 * ORIG_FEA];
  int a0 = blockIdx.x * 64;
  int na = min(64, N_ATOMS - a0);
  int tid = threadIdx.x;
  int c = tid & 63, rgrp = tid >> 6;
  float w[ORIG_FEA];
#pragma unroll
  for (int k = 0; k < ORIG_FEA; ++k) w[k] = W[k * AF + c];
  int n4 = na * (ORIG_FEA / 4);
  const float4* g4 = (const float4*)(af + (size_t)a0 * ORIG_FEA);
  float4* s4 = (float4*)saf;
  for (int e = tid; e < n4; e += 256) s4[e] = g4[e];
  __syncthreads();
  float bc = b[c];
  for (int a = rgrp; a < na; a += 4) {
    float acc = bc;
    const float4* row = (const float4*)(saf + a * ORIG_FEA);
#pragma unroll
    for (int q = 0; q < ORIG_FEA / 4; ++q) {
      float4 v = row[q];
      acc = fmaf(v.x, w[4 * q], acc);
      acc = fmaf(v.y, w[4 * q + 1], acc);
      acc = fmaf(v.z, w[4 * q + 2], acc);
      acc = fmaf(v.w, w[4 * q + 3], acc);
    }
    x[(size_t)(a0 + a) * AF + c] = acc;
  }
}

// y GEMM: [100k x 64] @ [64 x 256] -> y_self, y_nbr.
// UPD=1: fuses the PREVIOUS layer's BN2+softplus update into the x staging load
// (x_new = softplus(x + s*sc2 + sh2)), writing x_new back in place. Each ysn block
// owns its 80 atoms exclusively -> in-place is race-free. sc2/sh2 computed per-block
// from raw sums (replaces k_finalize2 + k_update entirely).
template <int UPD>
__global__ __launch_bounds__(256, 2) void k_ysn(
    const float* __restrict__ x, const float* __restrict__ s,
    const float* __restrict__ gsum2, const float* __restrict__ gsumsq2,
    const float* __restrict__ bn2g, const float* __restrict__ bn2b,
    const float* __restrict__ Wf,
    float* __restrict__ y_self, float* __restrict__ y_nbr,
    float* __restrict__ xout) {
  __shared__ __align__(16) float sW2[64 * 256];
  __shared__ __align__(16) float sx[YB_CHUNK * AF];
  __shared__ __align__(16) float ssc[AF], ssh[AF];
  int tid = threadIdx.x;
  int cg = tid & 31, ag = tid >> 5;     // cg: ch-quad, ag: atom-pair
  int c0 = cg * 4;
  if (UPD && tid < AF) {
    float m = gsum2[tid] * (1.0f / (float)N_ATOMS);
    float v = gsumsq2[tid] * (1.0f / (float)N_ATOMS) - m * m;
    float sc = bn2g[tid] * rsqrtf(v + EPS);
    ssc[tid] = sc;
    ssh[tid] = bn2b[tid] - m * sc;
  }
  {  // stage W': cols 0..127 = Wf[0:64][:], cols 128..255 = Wf[64:128][:]
    float4* s4 = (float4*)sW2;
    const float4* g4 = (const float4*)Wf;
    for (int e = tid; e < 64 * 64; e += 256) {
      int r = e >> 6, q = e & 63;
      s4[r * 64 + q] = (q < 32) ? g4[r * 32 + q] : g4[(64 + r) * 32 + (q - 32)];
    }
  }
  int ab = blockIdx.x * YB_ATOMS;
  for (int cc = 0; cc < YB_ATOMS / YB_CHUNK; ++cc) {
    int a0 = ab + cc * YB_CHUNK;
    __syncthreads();   // covers W/ssc staging on iter 0, prior compute after
    {
      float4* s4 = (float4*)sx;
      const float4* g4 = (const float4*)(x + (size_t)a0 * AF);
      for (int e = tid; e < YB_CHUNK * AF / 4; e += 256) {
        float4 xv = g4[e];
        if (UPD) {
          float4 sv = ((const float4*)(s + (size_t)a0 * AF))[e];
          int c4 = (e & 15) * 4;
          xv.x = softplus_f(fmaf(sv.x, ssc[c4 + 0], xv.x) + ssh[c4 + 0]);
          xv.y = softplus_f(fmaf(sv.y, ssc[c4 + 1], xv.y) + ssh[c4 + 1]);
          xv.z = softplus_f(fmaf(sv.z, ssc[c4 + 2], xv.z) + ssh[c4 + 2]);
          xv.w = softplus_f(fmaf(sv.w, ssc[c4 + 3], xv.w) + ssh[c4 + 3]);
          ((float4*)(xout + (size_t)a0 * AF))[e] = xv;
        }
        s4[e] = xv;
      }
    }
    __syncthreads();
    float4 accs[2] = {zero4(), zero4()};
    float4 accn[2] = {zero4(), zero4()};
    for (int k0 = 0; k0 < AF; k0 += 4) {
      float4 av0 = *(const float4*)(sx + (ag * 2 + 0) * AF + k0);
      float4 av1 = *(const float4*)(sx + (ag * 2 + 1) * AF + k0);
#pragma unroll
      for (int kk = 0; kk < 4; ++kk) {
        float4 b0 = *(const float4*)(sW2 + (k0 + kk) * 256 + c0);
        float4 b1 = *(const float4*)(sW2 + (k0 + kk) * 256 + 128 + c0);
        float s0 = (kk == 0) ? av0.x : (kk == 1) ? av0.y : (kk == 2) ? av0.z : av0.w;
        float s1 = (kk == 0) ? av1.x : (kk == 1) ? av1.y : (kk == 2) ? av1.z : av1.w;
        fma4(accs[0], s0, b0); fma4(accn[0], s0, b1);
        fma4(accs[1], s1, b0); fma4(accn[1], s1, b1);
      }
    }
#pragma unroll
    for (int t = 0; t < 2; ++t) {
      size_t n = (size_t)(a0 + ag * 2 + t);
      *(float4*)(y_self + n * OUT2 + c0) = accs[t];
      *(float4*)(y_nbr + n * OUT2 + c0) = accn[t];
    }
  }
}

// Edge GEMM micro-kernel: A fp16 from LDS (cvt at use), B f32 from LDS, f32 FMA.
__device__ __forceinline__ void edge_gemm(
    const _Float16* snf, const float* sW, int ebase, int c0,
    float4 acc0[6], float4 acc1[6]) {
#pragma unroll
  for (int e = 0; e < 6; ++e) { acc0[e] = zero4(); acc1[e] = zero4(); }
  for (int k0 = 0; k0 < 40; k0 += 4) {
    h4 av[6];
#pragma unroll
    for (int e = 0; e < 6; ++e)
      av[e] = *(const h4*)(snf + (ebase + e) * NF_STRIDE + k0);
#pragma unroll
    for (int kk = 0; kk < 4; ++kk) {
      float4 b0 = *(const float4*)(sW + (k0 + kk) * OUT2 + c0);
      float4 b1 = *(const float4*)(sW + (k0 + kk) * OUT2 + AF + c0);
#pragma unroll
      for (int e = 0; e < 6; ++e) {
        float s = (float)av[e][kk];
        fma4(acc0[e], s, b0);
        fma4(acc1[e], s, b1);
      }
    }
  }
  {  // k = 40 tail
    float4 b0 = *(const float4*)(sW + 40 * OUT2 + c0);
    float4 b1 = *(const float4*)(sW + 40 * OUT2 + AF + c0);
#pragma unroll
    for (int e = 0; e < 6; ++e) {
      float s = (float)snf[(ebase + e) * NF_STRIDE + 40];
      fma4(acc0[e], s, b0);
      fma4(acc1[e], s, b1);
    }
  }
}

// ---------------- FAST PATH pass 1: PERSISTENT blocks + double-buffered snf ----------
template <int WZ>
__global__ __launch_bounds__(256, 2) void k_zstats_p(
    const float* __restrict__ nbr_fea, const int* __restrict__ nidx,
    const float* __restrict__ y_self, const float* __restrict__ y_nbr,
    const float* __restrict__ Wf, const float* __restrict__ bf,
    float* __restrict__ gsum, float* __restrict__ gsumsq,
    __half* __restrict__ z16) {
  __shared__ __align__(16) _Float16 snf[2 * EDGES * NF_STRIDE];  // 2 x 16896 B
  __shared__ __align__(16) float sW[NBR_FEA * OUT2];             // 21504 B
  __shared__ __align__(16) unsigned char sbuf[1536];             // sidx[2] / reduce alias
  int tid = threadIdx.x;
  int cg = tid & 15, eg = tid >> 4;
  int c0 = cg * 4;
  {  // stage W once per (persistent) block
    float4* sW4 = (float4*)sW;
    const float4* gW4 = (const float4*)(Wf + 2 * AF * OUT2);
    for (int e = tid; e < NBR_FEA * (OUT2 / 4); e += 256) sW4[e] = gW4[e];
  }
  // prologue: stage chunk 0 into buffer 0
  {
    int a0 = blockIdx.x * ZCH;
    const float* gnf = nbr_fea + (size_t)a0 * M_NBR * NBR_FEA;
    _Float16* s = snf;
    int* si = (int*)sbuf;
    for (int e = tid; e < EDGES * NBR_FEA; e += 256) {
      int r = e / NBR_FEA;
      int k = e - r * NBR_FEA;
      s[r * NF_STRIDE + k] = (_Float16)gnf[e];
    }
    for (int e = tid; e < EDGES; e += 256) {
      s[e * NF_STRIDE + 41] = (_Float16)0.f;
      s[e * NF_STRIDE + 42] = (_Float16)0.f;
      s[e * NF_STRIDE + 43] = (_Float16)0.f;
      si[e] = nidx[(size_t)a0 * M_NBR + e];
    }
  }
  __syncthreads();
  float4 bz0 = *(const float4*)(bf + c0);
  float4 bz1 = *(const float4*)(bf + AF + c0);
  float4 sm0 = zero4(), sq0 = zero4(), sm1 = zero4(), sq1 = zero4();
  int buf = 0;
  for (int cc = blockIdx.x; cc < NCHUNKS; cc += ZP_BLOCKS) {
    int ccn = cc + ZP_BLOCKS;
    if (ccn < NCHUNKS) {
      int an = ccn * ZCH;
      const float* gnf = nbr_fea + (size_t)an * M_NBR * NBR_FEA;
      _Float16* s = snf + (buf ^ 1) * (EDGES * NF_STRIDE);
      int* si = (int*)sbuf + (buf ^ 1) * EDGES;
      for (int e = tid; e < EDGES * NBR_FEA; e += 256) {
        int r = e / NBR_FEA;
        int k = e - r * NBR_FEA;
        s[r * NF_STRIDE + k] = (_Float16)gnf[e];
      }
      for (int e = tid; e < EDGES; e += 256) {
        s[e * NF_STRIDE + 41] = (_Float16)0.f;
        s[e * NF_STRIDE + 42] = (_Float16)0.f;
        s[e * NF_STRIDE + 43] = (_Float16)0.f;
        si[e] = nidx[(size_t)an * M_NBR + e];
      }
    }
    int a0 = cc * ZCH;
    const _Float16* scur = snf + buf * (EDGES * NF_STRIDE);
    const int* sicur = (const int*)sbuf + buf * EDGES;
    for (int c = 0; c < 2; ++c) {
      int ebase = c * 96 + eg * 6;
      int atomL = c * 8 + (eg >> 1);
      const float* ys = y_self + (size_t)(a0 + atomL) * OUT2;
      float4 y0 = *(const float4*)(ys + c0);
      float4 y1 = *(const float4*)(ys + AF + c0);
      float4 acc0[6], acc1[6];
      edge_gemm(scur, sW, ebase, c0, acc0, acc1);
#pragma unroll
      for (int e = 0; e < 6; ++e) {
        int j = sicur[ebase + e];
        const float* yn = y_nbr + (size_t)j * OUT2;
        float4 n0 = *(const float4*)(yn + c0);
        float4 n1 = *(const float4*)(yn + AF + c0);
        float4 z0, z1;
        z0.x = acc0[e].x + y0.x + n0.x + bz0.x; z0.y = acc0[e].y + y0.y + n0.y + bz0.y;
        z0.z = acc0[e].z + y0.z + n0.z + bz0.z; z0.w = acc0[e].w + y0.w + n0.w + bz0.w;
        z1.x = acc1[e].x + y1.x + n1.x + bz1.x; z1.y = acc1[e].y + y1.y + n1.y + bz1.y;
        z1.z = acc1[e].z + y1.z + n1.z + bz1.z; z1.w = acc1[e].w + y1.w + n1.w + bz1.w;
        if (WZ) {
          __half* zp = z16 + ((size_t)a0 * M_NBR + ebase + e) * OUT2 + c0;
          store_h4(zp, z0);
          store_h4(zp + AF, z1);
        }
        sm0.x += z0.x; sm0.y += z0.y; sm0.z += z0.z; sm0.w += z0.w;
        sm1.x += z1.x; sm1.y += z1.y; sm1.z += z1.z; sm1.w += z1.w;
        sq0.x = fmaf(z0.x, z0.x, sq0.x); sq0.y = fmaf(z0.y, z0.y, sq0.y);
        sq0.z = fmaf(z0.z, z0.z, sq0.z); sq0.w = fmaf(z0.w, z0.w, sq0.w);
        sq1.x = fmaf(z1.x, z1.x, sq1.x); sq1.y = fmaf(z1.y, z1.y, sq1.y);
        sq1.z = fmaf(z1.z, z1.z, sq1.z); sq1.w = fmaf(z1.w, z1.w, sq1.w);
      }
    }
    __syncthreads();
    buf ^= 1;
  }
  // ---- once-per-block reduce ----
  float* lsum = (float*)sbuf;          // [OUT2]
  float* lsumsq = lsum + OUT2;         // [OUT2]
  ((float*)sbuf)[tid] = 0.f;
  __syncthreads();
  atomicAdd(&lsum[c0 + 0], sm0.x); atomicAdd(&lsum[c0 + 1], sm0.y);
  atomicAdd(&lsum[c0 + 2], sm0.z); atomicAdd(&lsum[c0 + 3], sm0.w);
  atomicAdd(&lsum[AF + c0 + 0], sm1.x); atomicAdd(&lsum[AF + c0 + 1], sm1.y);
  atomicAdd(&lsum[AF + c0 + 2], sm1.z); atomicAdd(&lsum[AF + c0 + 3], sm1.w);
  atomicAdd(&lsumsq[c0 + 0], sq0.x); atomicAdd(&lsumsq[c0 + 1], sq0.y);
  atomicAdd(&lsumsq[c0 + 2], sq0.z); atomicAdd(&lsumsq[c0 + 3], sq0.w);
  atomicAdd(&lsumsq[AF + c0 + 0], sq1.x); atomicAdd(&lsumsq[AF + c0 + 1], sq1.y);
  atomicAdd(&lsumsq[AF + c0 + 2], sq1.z); atomicAdd(&lsumsq[AF + c0 + 3], sq1.w);
  __syncthreads();
  if (tid < OUT2) {
    atomicAdd(&gsum[tid], lsum[tid]);
    atomicAdd(&gsumsq[tid], lsumsq[tid]);
  }
}

// ---------------- fallback-path machinery (ws too small) ----------------
__device__ __forceinline__ void stage_edge(
    const float* __restrict__ nbr_fea, const int* __restrict__ nidx,
    const float* __restrict__ We, int a0, int tid,
    _Float16* snf, float* sW, int* sidx) {
  float4* sW4 = (float4*)sW;
  const float4* gW4 = (const float4*)We;
  for (int e = tid; e < NBR_FEA * (OUT2 / 4); e += 256) sW4[e] = gW4[e];
  const float* gnf = nbr_fea + (size_t)a0 * M_NBR * NBR_FEA;
  for (int e = tid; e < EDGES * NBR_FEA; e += 256) {
    int r = e / NBR_FEA;
    int k = e - r * NBR_FEA;
    snf[r * NF_STRIDE + k] = (_Float16)gnf[e];
  }
  for (int e = tid; e < EDGES; e += 256) {
    snf[e * NF_STRIDE + 41] = (_Float16)0.f;
    snf[e * NF_STRIDE + 42] = (_Float16)0.f;
    snf[e * NF_STRIDE + 43] = (_Float16)0.f;
    sidx[e] = nidx[(size_t)a0 * M_NBR + e];
  }
}

__global__ __launch_bounds__(256, 2) void k_zstats_fb(
    const float* __restrict__ nbr_fea, const int* __restrict__ nidx,
    const float* __restrict__ y_self, const float* __restrict__ y_nbr,
    const float* __restrict__ Wf, const float* __restrict__ bf,
    float* __restrict__ gsum, float* __restrict__ gsumsq) {
  __shared__ __align__(16) _Float16 snf[EDGES * NF_STRIDE];
  __shared__ __align__(16) float sW[NBR_FEA * OUT2];
  __shared__ int sidx[EDGES];
  __shared__ float lsum[OUT2], lsumsq[OUT2];
  int tid = threadIdx.x;
  int cg = tid & 15, eg = tid >> 4;
  int c0 = cg * 4;
  if (tid < OUT2) { lsum[tid] = 0.f; lsumsq[tid] = 0.f; }
  int a0 = blockIdx.x * ZCH;
  stage_edge(nbr_fea, nidx, Wf + 2 * AF * OUT2, a0, tid, snf, sW, sidx);
  __syncthreads();
  float4 bz0 = *(const float4*)(bf + c0);
  float4 bz1 = *(const float4*)(bf + AF + c0);
  float4 sm0 = zero4(), sq0 = zero4(), sm1 = zero4(), sq1 = zero4();
  for (int c = 0; c < 2; ++c) {
    int ebase = c * 96 + eg * 6;
    int atomL = c * 8 + (eg >> 1);
    const float* ys = y_self + (size_t)(a0 + atomL) * OUT2;
    float4 y0 = *(const float4*)(ys + c0);
    float4 y1 = *(const float4*)(ys + AF + c0);
    float4 acc0[6], acc1[6];
    edge_gemm(snf, sW, ebase, c0, acc0, acc1);
#pragma unroll
    for (int e = 0; e < 6; ++e) {
      int j = sidx[ebase + e];
      const float* yn = y_nbr + (size_t)j * OUT2;
      float4 n0 = *(const float4*)(yn + c0);
      float4 n1 = *(const float4*)(yn + AF + c0);
      float4 z0, z1;
      z0.x = acc0[e].x + y0.x + n0.x + bz0.x; z0.y = acc0[e].y + y0.y + n0.y + bz0.y;
      z0.z = acc0[e].z + y0.z + n0.z + bz0.z; z0.w = acc0[e].w + y0.w + n0.w + bz0.w;
      z1.x = acc1[e].x + y1.x + n1.x + bz1.x; z1.y = acc1[e].y + y1.y + n1.y + bz1.y;
      z1.z = acc1[e].z + y1.z + n1.z + bz1.z; z1.w = acc1[e].w + y1.w + n1.w + bz1.w;
      sm0.x += z0.x; sm0.y += z0.y; sm0.z += z0.z; sm0.w += z0.w;
      sm1.x += z1.x; sm1.y += z1.y; sm1.z += z1.z; sm1.w += z1.w;
      sq0.x = fmaf(z0.x, z0.x, sq0.x); sq0.y = fmaf(z0.y, z0.y, sq0.y);
      sq0.z = fmaf(z0.z, z0.z, sq0.z); sq0.w = fmaf(z0.w, z0.w, sq0.w);
      sq1.x = fmaf(z1.x, z1.x, sq1.x); sq1.y = fmaf(z1.y, z1.y, sq1.y);
      sq1.z = fmaf(z1.z, z1.z, sq1.z); sq1.w = fmaf(z1.w, z1.w, sq1.w);
    }
  }
  atomicAdd(&lsum[c0 + 0], sm0.x); atomicAdd(&lsum[c0 + 1], sm0.y);
  atomicAdd(&lsum[c0 + 2], sm0.z); atomicAdd(&lsum[c0 + 3], sm0.w);
  atomicAdd(&lsum[AF + c0 + 0], sm1.x); atomicAdd(&lsum[AF + c0 + 1], sm1.y);
  atomicAdd(&lsum[AF + c0 + 2], sm1.z); atomicAdd(&lsum[AF + c0 + 3], sm1.w);
  atomicAdd(&lsumsq[c0 + 0], sq0.x); atomicAdd(&lsumsq[c0 + 1], sq0.y);
  atomicAdd(&lsumsq[c0 + 2], sq0.z); atomicAdd(&lsumsq[c0 + 3], sq0.w);
  atomicAdd(&lsumsq[AF + c0 + 0], sq1.x); atomicAdd(&lsumsq[AF + c0 + 1], sq1.y);
  atomicAdd(&lsumsq[AF + c0 + 2], sq1.z); atomicAdd(&lsumsq[AF + c0 + 3], sq1.w);
  __syncthreads();
  if (tid < OUT2) {
    atomicAdd(&gsum[tid], lsum[tid]);
    atomicAdd(&gsumsq[tid], lsumsq[tid]);
  }
}

// Pass 2 FAST PATH: pure stream over persisted z16.
// BN1 finalize fused: each block derives sc1/sh1 from raw sums (replaces k_finalize1).
__global__ __launch_bounds__(256, 4) void k_apply_stream(
    const __half* __restrict__ z16,
    const float* __restrict__ gsum1, const float* __restrict__ gsumsq1,
    const float* __restrict__ bn1g, const float* __restrict__ bn1b,
    float* __restrict__ s_out, float* __restrict__ gsum, float* __restrict__ gsumsq) {
  __shared__ __align__(16) float ssc1[OUT2], ssh1[OUT2];
  __shared__ float lsum[AF], lsumsq[AF];
  int tid = threadIdx.x;
  if (tid < AF) { lsum[tid] = 0.f; lsumsq[tid] = 0.f; }
  if (tid < OUT2) {
    const float inv = 1.0f / ((float)N_ATOMS * M_NBR);
    float m = gsum1[tid] * inv;
    float v = gsumsq1[tid] * inv - m * m;
    float sc = bn1g[tid] * rsqrtf(v + EPS);
    ssc1[tid] = sc;
    ssh1[tid] = bn1b[tid] - m * sc;
  }
  __syncthreads();
  int cg = tid & 15, a = tid >> 4;     // 16 atoms per block
  int c0 = cg * 4;
  size_t atom = (size_t)blockIdx.x * 16 + a;
  float4 f0 = *(const float4*)(ssc1 + c0);
  float4 g0 = *(const float4*)(ssh1 + c0);
  float4 f1 = *(const float4*)(ssc1 + AF + c0);
  float4 g1 = *(const float4*)(ssh1 + AF + c0);
  const __half* zr = z16 + atom * (M_NBR * OUT2);
  float4 sacc = zero4();
#pragma unroll 4
  for (int m = 0; m < M_NBR; ++m) {
    float4 zf = load_h4(zr + m * OUT2 + c0);
    float4 zc = load_h4(zr + m * OUT2 + AF + c0);
    zf.x = fmaf(zf.x, f0.x, g0.x); zf.y = fmaf(zf.y, f0.y, g0.y);
    zf.z = fmaf(zf.z, f0.z, g0.z); zf.w = fmaf(zf.w, f0.w, g0.w);
    zc.x = fmaf(zc.x, f1.x, g1.x); zc.y = fmaf(zc.y, f1.y, g1.y);
    zc.z = fmaf(zc.z, f1.z, g1.z); zc.w = fmaf(zc.w, f1.w, g1.w);
    sacc.x = fmaf(sigmoid_f(zf.x), softplus_f(zc.x), sacc.x);
    sacc.y = fmaf(sigmoid_f(zf.y), softplus_f(zc.y), sacc.y);
    sacc.z = fmaf(sigmoid_f(zf.z), softplus_f(zc.z), sacc.z);
    sacc.w = fmaf(sigmoid_f(zf.w), softplus_f(zc.w), sacc.w);
  }
  *(float4*)(s_out + atom * AF + c0) = sacc;
  float4 sq;
  sq.x = sacc.x * sacc.x; sq.y = sacc.y * sacc.y;
  sq.z = sacc.z * sacc.z; sq.w = sacc.w * sacc.w;
  sacc.x += __shfl_xor(sacc.x, 16, 64); sacc.y += __shfl_xor(sacc.y, 16, 64);
  sacc.z += __shfl_xor(sacc.z, 16, 64); sacc.w += __shfl_xor(sacc.w, 16, 64);
  sq.x += __shfl_xor(sq.x, 16, 64); sq.y += __shfl_xor(sq.y, 16, 64);
  sq.z += __shfl_xor(sq.z, 16, 64); sq.w += __shfl_xor(sq.w, 16, 64);
  sacc.x += __shfl_xor(sacc.x, 32, 64); sacc.y += __shfl_xor(sacc.y, 32, 64);
  sacc.z += __shfl_xor(sacc.z, 32, 64); sacc.w += __shfl_xor(sacc.w, 32, 64);
  sq.x += __shfl_xor(sq.x, 32, 64); sq.y += __shfl_xor(sq.y, 32, 64);
  sq.z += __shfl_xor(sq.z, 32, 64); sq.w += __shfl_xor(sq.w, 32, 64);
  if ((tid & 48) == 0) {
    atomicAdd(&lsum[c0 + 0], sacc.x); atomicAdd(&lsum[c0 + 1], sacc.y);
    atomicAdd(&lsum[c0 + 2], sacc.z); atomicAdd(&lsum[c0 + 3], sacc.w);
    atomicAdd(&lsumsq[c0 + 0], sq.x); atomicAdd(&lsumsq[c0 + 1], sq.y);
    atomicAdd(&lsumsq[c0 + 2], sq.z); atomicAdd(&lsumsq[c0 + 3], sq.w);
  }
  __syncthreads();
  if (tid < AF) {
    atomicAdd(&gsum[tid], lsum[tid]);
    atomicAdd(&gsumsq[tid], lsumsq[tid]);
  }
}

// Pass 2 FALLBACK (ws too small): recompute z. Takes precomputed sc1/sh1 (k_finalize).
__global__ __launch_bounds__(256, 2) void k_apply(
    const float* __restrict__ nbr_fea, const int* __restrict__ nidx,
    const float* __restrict__ y_self, const float* __restrict__ y_nbr,
    const float* __restrict__ Wf, const float* __restrict__ bf,
    const float* __restrict__ sc1, const float* __restrict__ sh1,
    float* __restrict__ s_out, float* __restrict__ gsum, float* __restrict__ gsumsq) {
  __shared__ __align__(16) _Float16 snf[EDGES * NF_STRIDE];
  __shared__ __align__(16) float sW[NBR_FEA * OUT2];
  __shared__ int sidx[EDGES];
  __shared__ float lsum[AF], lsumsq[AF];
  int tid = threadIdx.x;
  int cg = tid & 15, eg = tid >> 4;
  int c0 = cg * 4;
  if (tid < AF) { lsum[tid] = 0.f; lsumsq[tid] = 0.f; }
  int a0 = blockIdx.x * ZCH;
  stage_edge(nbr_fea, nidx, Wf + 2 * AF * OUT2, a0, tid, snf, sW, sidx);
  __syncthreads();
  float4 bz0 = *(const float4*)(bf + c0);
  float4 bz1 = *(const float4*)(bf + AF + c0);
  float4 f0 = *(const float4*)(sc1 + c0);
  float4 g0 = *(const float4*)(sh1 + c0);
  float4 f1 = *(const float4*)(sc1 + AF + c0);
  float4 g1 = *(const float4*)(sh1 + AF + c0);
  for (int c = 0; c < 2; ++c) {
    int ebase = c * 96 + eg * 6;
    int atomL = c * 8 + (eg >> 1);
    const float* ys = y_self + (size_t)(a0 + atomL) * OUT2;
    float4 y0 = *(const float4*)(ys + c0);
    float4 y1 = *(const float4*)(ys + AF + c0);
    float4 acc0[6], acc1[6];
    edge_gemm(snf, sW, ebase, c0, acc0, acc1);
    float4 sacc = zero4();
#pragma unroll
    for (int e = 0; e < 6; ++e) {
      int j = sidx[ebase + e];
      const float* yn = y_nbr + (size_t)j * OUT2;
      float4 n0 = *(const float4*)(yn + c0);
      float4 n1 = *(const float4*)(yn + AF + c0);
      float4 z0, z1;
      z0.x = fmaf(acc0[e].x + y0.x + n0.x + bz0.x, f0.x, g0.x);
      z0.y = fmaf(acc0[e].y + y0.y + n0.y + bz0.y, f0.y, g0.y);
      z0.z = fmaf(acc0[e].z + y0.z + n0.z + bz0.z, f0.z, g0.z);
      z0.w = fmaf(acc0[e].w + y0.w + n0.w + bz0.w, f0.w, g0.w);
      z1.x = fmaf(acc1[e].x + y1.x + n1.x + bz1.x, f1.x, g1.x);
      z1.y = fmaf(acc1[e].y + y1.y + n1.y + bz1.y, f1.y, g1.y);
      z1.z = fmaf(acc1[e].z + y1.z + n1.z + bz1.z, f1.z, g1.z);
      z1.w = fmaf(acc1[e].w + y1.w + n1.w + bz1.w, f1.w, g1.w);
      sacc.x = fmaf(sigmoid_f(z0.x), softplus_f(z1.x), sacc.x);
      sacc.y = fmaf(sigmoid_f(z0.y), softplus_f(z1.y), sacc.y);
      sacc.z = fmaf(sigmoid_f(z0.z), softplus_f(z1.z), sacc.z);
      sacc.w = fmaf(sigmoid_f(z0.w), softplus_f(z1.w), sacc.w);
    }
    sacc.x += __shfl_xor(sacc.x, 16, 64);
    sacc.y += __shfl_xor(sacc.y, 16, 64);
    sacc.z += __shfl_xor(sacc.z, 16, 64);
    sacc.w += __shfl_xor(sacc.w, 16, 64);
    if ((eg & 1) == 0) {
      *(float4*)(s_out + (size_t)(a0 + atomL) * AF + c0) = sacc;
      atomicAdd(&lsum[c0 + 0], sacc.x); atomicAdd(&lsum[c0 + 1], sacc.y);
      atomicAdd(&lsum[c0 + 2], sacc.z); atomicAdd(&lsum[c0 + 3], sacc.w);
      atomicAdd(&lsumsq[c0 + 0], sacc.x * sacc.x);
      atomicAdd(&lsumsq[c0 + 1], sacc.y * sacc.y);
      atomicAdd(&lsumsq[c0 + 2], sacc.z * sacc.z);
      atomicAdd(&lsumsq[c0 + 3], sacc.w * sacc.w);
    }
  }
  __syncthreads();
  if (tid < AF) {
    atomicAdd(&gsum[tid], lsum[tid]);
    atomicAdd(&gsumsq[tid], lsumsq[tid]);
  }
}

__global__ void k_finalize(const float* __restrict__ gsum, const float* __restrict__ gsumsq,
                           const float* __restrict__ gamma, const float* __restrict__ beta,
                           float* __restrict__ scale, float* __restrict__ shift,
                           int chn, float invcount) {
  int c = threadIdx.x;
  if (c < chn) {
    float m = gsum[c] * invcount;
    float v = gsumsq[c] * invcount - m * m;
    float sc = gamma[c] * rsqrtf(v + EPS);
    scale[c] = sc;
    shift[c] = beta[c] - m * sc;
  }
}

// Pool with the FINAL layer's BN2+softplus update fused (crystal_atom_idx covers
// each atom exactly once, so applying on the fly is exact and x is never rewritten).
__global__ __launch_bounds__(128) void k_pool(
    const float* __restrict__ x, const float* __restrict__ s,
    const float* __restrict__ gsum2, const float* __restrict__ gsumsq2,
    const float* __restrict__ bn2g, const float* __restrict__ bn2b,
    const int* __restrict__ cidx,
    const float* __restrict__ Wp, const float* __restrict__ bp,
    float* __restrict__ out) {
  __shared__ float ssc[AF], ssh[AF];
  __shared__ float part[2][AF];
  __shared__ float mean[AF];
  int g = blockIdx.x, tid = threadIdx.x;
  if (tid < AF) {
    float m = gsum2[tid] * (1.0f / (float)N_ATOMS);
    float v = gsumsq2[tid] * (1.0f / (float)N_ATOMS) - m * m;
    float sc = bn2g[tid] * rsqrtf(v + EPS);
    ssc[tid] = sc;
    ssh[tid] = bn2b[tid] - m * sc;
  }
  __syncthreads();
  int c = tid & 63, h = tid >> 6;
  float scc = ssc[c], shc = ssh[c];
  float acc = 0.f;
  for (int a = h; a < ATOMS_PER; a += 2) {
    int idx = cidx[g * ATOMS_PER + a];
    float xv = x[(size_t)idx * AF + c];
    float sv = s[(size_t)idx * AF + c];
    acc += softplus_f(fmaf(sv, scc, xv) + shc);
  }
  part[h][c] = acc;
  __syncthreads();
  if (tid < AF) mean[tid] = (part[0][tid] + part[1][tid]) * (1.0f / ATOMS_PER);
  __syncthreads();
  float o = bp[tid];
#pragma unroll
  for (int k = 0; k < AF; ++k) o += mean[k] * Wp[k * OUT_DIM + tid];
  out[(size_t)g * OUT_DIM + tid] = fmaxf(o, 0.f);
}

extern "C" void kernel_launch(void* const* d_in, const int* in_sizes, int n_in,
                              void* d_out, int out_size, void* d_ws, size_t ws_size,
                              hipStream_t stream) {
  const float* atom_fea = (const float*)d_in[0];
  const float* nbr_fea  = (const float*)d_in[1];
  const int*   nbr_idx  = (const int*)d_in[2];
  const int*   cidx     = (const int*)d_in[3];
  const float* W_embed  = (const float*)d_in[4];
  const float* b_embed  = (const float*)d_in[5];
  const float* W_full   = (const float*)d_in[6];
  const float* b_full   = (const float*)d_in[7];
  const float* bn1_g    = (const float*)d_in[8];
  const float* bn1_b    = (const float*)d_in[9];
  const float* bn2_g    = (const float*)d_in[10];
  const float* bn2_b    = (const float*)d_in[11];
  const float* W_pool   = (const float*)d_in[12];
  const float* b_pool   = (const float*)d_in[13];
  float* out = (float*)d_out;

  float* ws = (float*)d_ws;
  size_t off = 0;
  float* x      = ws + off; off += (size_t)N_ATOMS * AF;
  float* y_self = ws + off; off += (size_t)N_ATOMS * OUT2;
  float* y_nbr  = ws + off; off += (size_t)N_ATOMS * OUT2;
  float* s_buf  = ws + off; off += (size_t)N_ATOMS * AF;
  float* sums   = ws + off; off += (size_t)N_CONV * 384;   // sum1/sumsq1/sum2/sumsq2
  float* affine = ws + off; off += (size_t)N_CONV * 384;   // sc1/sh1 (fallback only)

  size_t base_bytes = (off * sizeof(float) + 255) & ~(size_t)255;  // 256B align z16
  size_t z_bytes = (size_t)N_ATOMS * M_NBR * OUT2 * sizeof(__half);   // 307.2 MB
  bool fast = ws_size >= base_bytes + z_bytes;
  __half* z16 = fast ? (__half*)((char*)d_ws + base_bytes) : nullptr;

  hipMemsetAsync(sums, 0, (size_t)N_CONV * 384 * sizeof(float), stream);

  k_embed<<<(N_ATOMS + 63) / 64, 256, 0, stream>>>(atom_fea, W_embed, b_embed, x);

  for (int i = 0; i < N_CONV; ++i) {
    const float* Wf = W_full + (size_t)i * IN_FULL * OUT2;
    const float* bf = b_full + (size_t)i * OUT2;
    float* sum1   = sums + (size_t)i * 384;
    float* sumsq1 = sum1 + OUT2;
    float* sum2   = sumsq1 + OUT2;
    float* sumsq2 = sum2 + AF;
    float* sc1 = affine + (size_t)i * 384;
    float* sh1 = sc1 + OUT2;

    if (i == 0) {
      k_ysn<0><<<N_ATOMS / YB_ATOMS, 256, 0, stream>>>(
          x, nullptr, nullptr, nullptr, nullptr, nullptr, Wf, y_self, y_nbr, nullptr);
    } else {
      float* psum2   = sums + (size_t)(i - 1) * 384 + 2 * OUT2;
      float* psumsq2 = psum2 + AF;
      k_ysn<1><<<N_ATOMS / YB_ATOMS, 256, 0, stream>>>(
          x, s_buf, psum2, psumsq2, bn2_g + (i - 1) * AF, bn2_b + (i - 1) * AF,
          Wf, y_self, y_nbr, x);
    }
    if (fast) {
      k_zstats_p<1><<<ZP_BLOCKS, 256, 0, stream>>>(
          nbr_fea, nbr_idx, y_self, y_nbr, Wf, bf, sum1, sumsq1, z16);
      k_apply_stream<<<N_ATOMS / 16, 256, 0, stream>>>(
          z16, sum1, sumsq1, bn1_g + i * OUT2, bn1_b + i * OUT2,
          s_buf, sum2, sumsq2);
    } else {
      k_zstats_fb<<<N_ATOMS / ZCH, 256, 0, stream>>>(
          nbr_fea, nbr_idx, y_self, y_nbr, Wf, bf, sum1, sumsq1);
      k_finalize<<<1, 128, 0, stream>>>(sum1, sumsq1, bn1_g + i * OUT2, bn1_b + i * OUT2,
                                        sc1, sh1, OUT2, 1.0f / ((float)N_ATOMS * M_NBR));
      k_apply<<<N_ATOMS / ZCH, 256, 0, stream>>>(nbr_fea, nbr_idx, y_self, y_nbr,
                                                 Wf, bf, sc1, sh1, s_buf, sum2, sumsq2);
    }
  }

  {  // pool with final-layer update fused
    float* fsum2   = sums + (size_t)(N_CONV - 1) * 384 + 2 * OUT2;
    float* fsumsq2 = fsum2 + AF;
    k_pool<<<N_CRYSTALS, 128, 0, stream>>>(
        x, s_buf, fsum2, fsumsq2, bn2_g + (N_CONV - 1) * AF, bn2_b + (N_CONV - 1) * AF,
        cidx, W_pool, b_pool, out);
  }
}